// Round 6
// baseline (360.467 us; speedup 1.0000x reference)
//
#include <hip/hip_runtime.h>
#include <hip/hip_bf16.h>

#define NBANDS 5
#define BATCH  16
#define DIM    256
#define NNODE  64
#define SEQ    5
#define NHEAD  4
#define DHEAD  64

typedef __hip_bfloat16 bf16;
typedef unsigned short ushort_t;
typedef __attribute__((ext_vector_type(8))) short short8;   // 8 bf16 (4 VGPRs)
typedef __attribute__((ext_vector_type(4))) float float4v;  // 4 fp32 acc

__device__ __forceinline__ float bu2f(ushort_t u){
    bf16 h = *reinterpret_cast<bf16*>(&u);
    return __bfloat162float(h);
}
__device__ __forceinline__ ushort_t f2bu(float x){
    bf16 h = __float2bfloat16(x);
    return *reinterpret_cast<ushort_t*>(&h);
}

// ============ k_head: bases + weight prep (MFMA transposes + tail bf16) + feature transpose ============
// blocks [0,80):   local sbase, 4 rows/block
// block  80:       global gbase
// blocks [81,321): w1/gw transpose+convert (15 insts x 16 tiles)
// blocks [321,401): feature -> xtb [k,b,n,d] + xtT [k,b,d,n]
// blocks [401,593): tail weights fp32 -> bf16 straight convert (192 x 5120 elems)
__global__ void __launch_bounds__(256) k_head(
    const float* __restrict__ l_adj_w, const float* __restrict__ l_pos_enc,
    const float* __restrict__ l_pf,
    const float* __restrict__ g_adj_w, const float* __restrict__ g_pos_enc,
    const float* __restrict__ g_pf,
    float* __restrict__ sbase, float* __restrict__ gbase,
    const float* __restrict__ w1, const float* __restrict__ gw,
    ushort_t* __restrict__ w1bt, ushort_t* __restrict__ gwbt,
    const float* __restrict__ feat,
    ushort_t* __restrict__ xtb, ushort_t* __restrict__ xtT,
    const float* __restrict__ qkv_w, const float* __restrict__ attn_ow,
    const float* __restrict__ mlp_w1, const float* __restrict__ mlp_w2,
    const float* __restrict__ g_sim_w1, const float* __restrict__ g_gcn_w,
    ushort_t* __restrict__ tailw)
{
    int blk = blockIdx.x;
    int tid = threadIdx.x;
    __shared__ ushort_t tile[64][65];

    if (blk < 80) {
        // local bases: row r = blk*4 + wave
        int r = blk*4 + (tid>>6);
        int k = r >> 6, i = r & 63;
        int t = tid & 63;
        float aw = l_adj_w[(k*NNODE + i)*NNODE + t];
        float pe = l_pos_enc[(k*NNODE + i)*NNODE + t];
        float m1 = aw, m2 = pe;
        for (int o=32;o>0;o>>=1){ m1 = fmaxf(m1, __shfl_xor(m1,o,64)); m2 = fmaxf(m2, __shfl_xor(m2,o,64)); }
        float e1 = __expf(aw-m1), e2 = __expf(pe-m2);
        float s1=e1, s2=e2;
        for (int o=32;o>0;o>>=1){ s1 += __shfl_xor(s1,o,64); s2 += __shfl_xor(s2,o,64); }
        float pf = l_pf[k];
        sbase[(k*NNODE+i)*NNODE + t] = e1/s1 + pf*(e2/s2);
    } else if (blk == 80) {
        if (tid < NBANDS) {
            int i = tid;
            float r1[NBANDS], r2[NBANDS];
            float m1=-1e30f, m2=-1e30f;
            for (int j=0;j<NBANDS;j++){
                r1[j]=g_adj_w[i*NBANDS+j]; r2[j]=g_pos_enc[i*NBANDS+j];
                m1=fmaxf(m1,r1[j]); m2=fmaxf(m2,r2[j]);
            }
            float s1=0.f,s2=0.f;
            for (int j=0;j<NBANDS;j++){ r1[j]=__expf(r1[j]-m1); r2[j]=__expf(r2[j]-m2); s1+=r1[j]; s2+=r2[j]; }
            float pf = g_pf[0];
            for (int j=0;j<NBANDS;j++) gbase[i*NBANDS+j] = r1[j]/s1 + pf*(r2[j]/s2);
        }
    } else if (blk < 321) {
        // MFMA weight transpose: w1bt / gwbt
        int idx = blk - 81;
        int inst = idx >> 4;
        int t = idx & 15;
        int r0 = (t>>2)*64, c0 = (t&3)*64;
        const float* src; ushort_t* dst;
        if (inst < 10){
            int k = inst>>1, half = inst&1;
            src = w1  + ((size_t)k*512 + half*256)*256;
            dst = w1bt+ ((size_t)k*512 + half*256)*256;
        } else {
            int k = inst-10;
            src = gw  + (size_t)k*65536;
            dst = gwbt+ (size_t)k*65536;
        }
        int jj = tid & 63, i4 = tid >> 6;
        for (int p=0;p<16;p++){
            int i = p*4 + i4;
            tile[i][jj] = f2bu(src[(size_t)(r0+i)*256 + c0 + jj]);
        }
        __syncthreads();
        for (int p=0;p<16;p++){
            int i = p*4 + i4;
            dst[(size_t)(c0+i)*256 + r0 + jj] = tile[jj][i];
        }
    } else if (blk < 401) {
        // feature transpose
        int idx = blk - 321;
        int k = idx / BATCH, b = idx % BATCH;
        const float* src = feat + ((size_t)b*NBANDS*DIM + (size_t)k*DIM)*NNODE; // [D][N]
        ushort_t* dst = xtb + (size_t)(k*BATCH+b)*NNODE*DIM;                    // [N][D]
        ushort_t* dstT = xtT + (size_t)(k*BATCH+b)*DIM*NNODE;                   // [D][N]
        for (int u=0; u<64; ++u){
            int i = u*256 + tid;
            dstT[i] = f2bu(src[i]);
        }
        for (int dt=0; dt<4; ++dt){
            for (int r=0;r<16;r++){
                int dp = r*4 + (tid>>6);
                int n  = tid & 63;
                tile[dp][n] = f2bu(src[(size_t)(dt*64+dp)*NNODE + n]);
            }
            __syncthreads();
            for (int r=0;r<16;r++){
                int n  = r*4 + (tid>>6);
                int dp = tid & 63;
                dst[(size_t)n*DIM + dt*64 + dp] = tile[dp][n];
            }
            __syncthreads();
        }
    } else {
        // tail weight bf16 conversion; segments contiguous in tailw
        size_t base = (size_t)(blk-401)*5120;
        for (int i=0;i<20;i++){
            size_t gidx = base + (size_t)i*256 + tid;
            const float* src; size_t off;
            if (gidx < 196608)      { src=qkv_w;    off=gidx; }
            else if (gidx < 262144) { src=attn_ow;  off=gidx-196608; }
            else if (gidx < 524288) { src=mlp_w1;   off=gidx-262144; }
            else if (gidx < 786432) { src=mlp_w2;   off=gidx-524288; }
            else if (gidx < 917504) { src=g_sim_w1; off=gidx-786432; }
            else                    { src=g_gcn_w;  off=gidx-917504; }
            tailw[gidx] = f2bu(src[off]);
        }
    }
}

// ---- MFMA a/bp: per band GEMM [1024 x 256] @ [256 x 512] -> aab|bbb bf16 ----
__global__ void __launch_bounds__(256) k_ab_mfma(const ushort_t* __restrict__ xtb,
                        const ushort_t* __restrict__ w1bt, const float* __restrict__ b1,
                        ushort_t* __restrict__ aab, ushort_t* __restrict__ bbb)
{
    int blk = blockIdx.x;                 // 5*16*8
    int kband = blk / (BATCH*8);
    int b = (blk/8) % BATCH;
    int nblk = blk & 7;
    int tid = threadIdx.x;
    int wave = tid>>6, lane = tid&63;
    int c16 = lane & 15, quad = lane >> 4;
    int m0 = wave*16;
    size_t rowbase = (size_t)(kband*BATCH+b)*NNODE;
    const ushort_t* Aptr = xtb + (rowbase + m0 + c16)*DIM + quad*8;
    const ushort_t* Bbase = w1bt + (size_t)kband*512*DIM;
    int ncol0 = nblk*64;
    const ushort_t* Bptr0 = Bbase + (size_t)(ncol0 +  0 + c16)*DIM + quad*8;
    const ushort_t* Bptr1 = Bbase + (size_t)(ncol0 + 16 + c16)*DIM + quad*8;
    const ushort_t* Bptr2 = Bbase + (size_t)(ncol0 + 32 + c16)*DIM + quad*8;
    const ushort_t* Bptr3 = Bbase + (size_t)(ncol0 + 48 + c16)*DIM + quad*8;
    float4v acc0 = {0.f,0.f,0.f,0.f}, acc1 = acc0, acc2 = acc0, acc3 = acc0;
    #pragma unroll
    for (int ks=0; ks<8; ++ks){
        short8 a  = *reinterpret_cast<const short8*>(Aptr  + ks*32);
        short8 b0 = *reinterpret_cast<const short8*>(Bptr0 + ks*32);
        short8 b1v= *reinterpret_cast<const short8*>(Bptr1 + ks*32);
        short8 b2 = *reinterpret_cast<const short8*>(Bptr2 + ks*32);
        short8 b3 = *reinterpret_cast<const short8*>(Bptr3 + ks*32);
        acc0 = __builtin_amdgcn_mfma_f32_16x16x32_bf16(a, b0, acc0, 0,0,0);
        acc1 = __builtin_amdgcn_mfma_f32_16x16x32_bf16(a, b1v, acc1, 0,0,0);
        acc2 = __builtin_amdgcn_mfma_f32_16x16x32_bf16(a, b2, acc2, 0,0,0);
        acc3 = __builtin_amdgcn_mfma_f32_16x16x32_bf16(a, b3, acc3, 0,0,0);
    }
    int half = nblk >> 2;
    int cbase = (nblk & 3)*64;
    ushort_t* dst = half ? bbb : aab;
    float4v accs[4] = {acc0, acc1, acc2, acc3};
    #pragma unroll
    for (int nt=0; nt<4; ++nt){
        int cg = cbase + nt*16 + c16;
        float bias = half ? 0.f : b1[kband*DIM + cg];
        #pragma unroll
        for (int r=0;r<4;r++){
            int m = m0 + quad*4 + r;
            dst[(rowbase + m)*DIM + cg] = f2bu(accs[nt][r] + bias);
        }
    }
}

// ------- dyn = sigmoid(sum_d elu(a_i+bp_j)*w2 + b2); comb = softmax (bf16) ---
__global__ void k_dyn_comb(const ushort_t* __restrict__ aab,
                           const ushort_t* __restrict__ bbb,
                           const float* __restrict__ w2, const float* __restrict__ b2arr,
                           const float* __restrict__ sbase,
                           ushort_t* __restrict__ combb)
{
    int blk = blockIdx.x;                     // NBANDS*BATCH*16 blocks, 4 i-rows each
    int k = blk / (BATCH*16);
    int b = (blk / 16) % BATCH;
    int i0 = (blk % 16) * 4;
    int kb = k*BATCH + b;
    __shared__ float arows[4][DIM];
    __shared__ float w2s[DIM];
    __shared__ float dyn_s[4][NNODE];
    int tid = threadIdx.x;
    int wave = tid >> 6, lane = tid & 63;
    for (int r=0;r<4;r++) arows[r][tid] = bu2f(aab[((size_t)kb*NNODE + i0 + r)*DIM + tid]);
    w2s[tid] = w2[k*DIM + tid];
    __syncthreads();
    const ushort_t* bpbase = bbb + (size_t)kb*NNODE*DIM;
    for (int jt=0; jt<16; ++jt){
        int j = jt*4 + wave;
        const ushort_t* bj = bpbase + (size_t)j*DIM;
        float acc[4] = {0.f,0.f,0.f,0.f};
        #pragma unroll
        for (int m=0;m<4;m++){
            int dd = lane + m*64;
            float bpv = bu2f(bj[dd]);
            float wv  = w2s[dd];
            #pragma unroll
            for (int r=0;r<4;r++){
                float v = arows[r][dd] + bpv;
                float e = (v > 0.f) ? v : (__expf(v) - 1.f);   // elu
                acc[r] += e*wv;
            }
        }
        #pragma unroll
        for (int r=0;r<4;r++){
            float s = acc[r];
            for (int o=32;o>0;o>>=1) s += __shfl_xor(s,o,64);
            if (lane==0) dyn_s[r][j] = s;
        }
    }
    __syncthreads();
    {
        float sb2 = b2arr[k];
        float t = dyn_s[wave][lane] + sb2;
        float sg = 1.f/(1.f + __expf(-t));
        float val = sbase[(k*NNODE + i0 + wave)*NNODE + lane] + sg;
        float m = val;
        for (int o=32;o>0;o>>=1) m = fmaxf(m, __shfl_xor(m,o,64));
        float e = __expf(val - m);
        float s = e;
        for (int o=32;o>0;o>>=1) s += __shfl_xor(s,o,64);
        combb[((size_t)kb*NNODE + i0 + wave)*NNODE + lane] = f2bu(e/s);
    }
}

// ---- MFMA y: per (k,b) GEMM [64 x 64] @ [64 x 256] -> yb bf16 [kb][n][d] ----
__global__ void __launch_bounds__(256) k_y_mfma(const ushort_t* __restrict__ combb,
                       const ushort_t* __restrict__ xtT,
                       ushort_t* __restrict__ yb)
{
    int blk = blockIdx.x;                 // 5*16*4
    int kband = blk / (BATCH*4);
    int b = (blk/4) % BATCH;
    int nblk = blk & 3;
    int tid = threadIdx.x;
    int wave = tid>>6, lane = tid&63;
    int c16 = lane & 15, quad = lane >> 4;
    int m0 = wave*16;
    int kb = kband*BATCH + b;
    const ushort_t* Aptr = combb + ((size_t)kb*NNODE + m0 + c16)*NNODE + quad*8;  // [n][j]
    const ushort_t* Bbase = xtT + (size_t)kb*DIM*NNODE;                            // [d][j]
    int ncol0 = nblk*64;
    const ushort_t* Bptr0 = Bbase + (size_t)(ncol0 +  0 + c16)*NNODE + quad*8;
    const ushort_t* Bptr1 = Bbase + (size_t)(ncol0 + 16 + c16)*NNODE + quad*8;
    const ushort_t* Bptr2 = Bbase + (size_t)(ncol0 + 32 + c16)*NNODE + quad*8;
    const ushort_t* Bptr3 = Bbase + (size_t)(ncol0 + 48 + c16)*NNODE + quad*8;
    float4v acc0 = {0.f,0.f,0.f,0.f}, acc1 = acc0, acc2 = acc0, acc3 = acc0;
    #pragma unroll
    for (int ks=0; ks<2; ++ks){
        short8 a  = *reinterpret_cast<const short8*>(Aptr  + ks*32);
        short8 b0 = *reinterpret_cast<const short8*>(Bptr0 + ks*32);
        short8 b1v= *reinterpret_cast<const short8*>(Bptr1 + ks*32);
        short8 b2 = *reinterpret_cast<const short8*>(Bptr2 + ks*32);
        short8 b3 = *reinterpret_cast<const short8*>(Bptr3 + ks*32);
        acc0 = __builtin_amdgcn_mfma_f32_16x16x32_bf16(a, b0, acc0, 0,0,0);
        acc1 = __builtin_amdgcn_mfma_f32_16x16x32_bf16(a, b1v, acc1, 0,0,0);
        acc2 = __builtin_amdgcn_mfma_f32_16x16x32_bf16(a, b2, acc2, 0,0,0);
        acc3 = __builtin_amdgcn_mfma_f32_16x16x32_bf16(a, b3, acc3, 0,0,0);
    }
    size_t rowbase = (size_t)kb*NNODE;
    float4v accs[4] = {acc0, acc1, acc2, acc3};
    #pragma unroll
    for (int nt=0; nt<4; ++nt){
        int cg = ncol0 + nt*16 + c16;
        #pragma unroll
        for (int r=0;r<4;r++){
            int m = m0 + quad*4 + r;
            yb[(rowbase + m)*DIM + cg] = f2bu(accs[nt][r]);
        }
    }
}

// ---- MFMA gcn: [64 x 256] @ [256 x 256] + bias -> out_local f32 [b,k,d,n] ----
__global__ void __launch_bounds__(256) k_gcn_mfma(const ushort_t* __restrict__ yb,
                         const ushort_t* __restrict__ gwbt, const float* __restrict__ gb,
                         float* __restrict__ out_local)
{
    int blk = blockIdx.x;                 // 5*16*4
    int kband = blk / (BATCH*4);
    int b = (blk/4) % BATCH;
    int nblk = blk & 3;
    int tid = threadIdx.x;
    int wave = tid>>6, lane = tid&63;
    int c16 = lane & 15, quad = lane >> 4;
    int m0 = wave*16;
    int kb = kband*BATCH + b;
    const ushort_t* Aptr = yb + ((size_t)kb*NNODE + m0 + c16)*DIM + quad*8;  // [n][d]
    const ushort_t* Bbase = gwbt + (size_t)kband*DIM*DIM;                    // [col][kk]
    int ncol0 = nblk*64;
    const ushort_t* Bptr0 = Bbase + (size_t)(ncol0 +  0 + c16)*DIM + quad*8;
    const ushort_t* Bptr1 = Bbase + (size_t)(ncol0 + 16 + c16)*DIM + quad*8;
    const ushort_t* Bptr2 = Bbase + (size_t)(ncol0 + 32 + c16)*DIM + quad*8;
    const ushort_t* Bptr3 = Bbase + (size_t)(ncol0 + 48 + c16)*DIM + quad*8;
    float4v acc0 = {0.f,0.f,0.f,0.f}, acc1 = acc0, acc2 = acc0, acc3 = acc0;
    #pragma unroll
    for (int ks=0; ks<8; ++ks){
        short8 a  = *reinterpret_cast<const short8*>(Aptr  + ks*32);
        short8 b0 = *reinterpret_cast<const short8*>(Bptr0 + ks*32);
        short8 b1v= *reinterpret_cast<const short8*>(Bptr1 + ks*32);
        short8 b2 = *reinterpret_cast<const short8*>(Bptr2 + ks*32);
        short8 b3 = *reinterpret_cast<const short8*>(Bptr3 + ks*32);
        acc0 = __builtin_amdgcn_mfma_f32_16x16x32_bf16(a, b0, acc0, 0,0,0);
        acc1 = __builtin_amdgcn_mfma_f32_16x16x32_bf16(a, b1v, acc1, 0,0,0);
        acc2 = __builtin_amdgcn_mfma_f32_16x16x32_bf16(a, b2, acc2, 0,0,0);
        acc3 = __builtin_amdgcn_mfma_f32_16x16x32_bf16(a, b3, acc3, 0,0,0);
    }
    float4v accs[4] = {acc0, acc1, acc2, acc3};
    #pragma unroll
    for (int nt=0; nt<4; ++nt){
        int cg = ncol0 + nt*16 + c16;
        float bias = gb[kband*DIM + cg];
        float4 v = make_float4(accs[nt][0]+bias, accs[nt][1]+bias, accs[nt][2]+bias, accs[nt][3]+bias);
        float* dst = out_local + ((size_t)(b*NBANDS + kband)*DIM + cg)*NNODE + m0 + quad*4;
        *reinterpret_cast<float4*>(dst) = v;
    }
}

// ---------------- block LayerNorm over 256 elems ----------------------------
__device__ __forceinline__ float block_ln(float v, int tid, float* red, float g, float bln)
{
    float s = v;
    for (int o=32;o>0;o>>=1) s += __shfl_xor(s,o,64);
    int wave = tid>>6, lane = tid&63;
    if (lane==0) red[wave] = s;
    __syncthreads();
    float mean = (red[0]+red[1]+red[2]+red[3]) * (1.f/DIM);
    float c = v - mean;
    float q = c*c;
    for (int o=32;o>0;o>>=1) q += __shfl_xor(q,o,64);
    __syncthreads();
    if (lane==0) red[wave] = q;
    __syncthreads();
    float var = (red[0]+red[1]+red[2]+red[3]) * (1.f/DIM);
    return c * rsqrtf(var + 1e-5f) * g + bln;
}

// ============ k_tail: one block per batch — scale..final fused ============
// tailw layout: qkvb(196608) | owb(65536) | w1b(262144) | w2b(262144) | gw1b(131072) | ggwb(65536)
__global__ void __launch_bounds__(256) k_tail(
    const float* __restrict__ out_local,
    const ushort_t* __restrict__ tailw,
    const float* __restrict__ qkv_bias, const float* __restrict__ ob,
    const float* __restrict__ ln1_g, const float* __restrict__ ln1_b,
    const float* __restrict__ mb1, const float* __restrict__ mb2,
    const float* __restrict__ ln2_g, const float* __restrict__ ln2_b,
    const float* __restrict__ gb1,
    const float* __restrict__ gw2, const float* __restrict__ gb2,
    const float* __restrict__ gbase,
    const float* __restrict__ ggb,
    const float* __restrict__ imp_w, const float* __restrict__ imp_b,
    float* __restrict__ out0, float* __restrict__ out_gadj)
{
    const ushort_t* qkvb = tailw;
    const ushort_t* owb  = qkvb + 196608;
    const ushort_t* w1b  = owb  + 65536;
    const ushort_t* w2b  = w1b  + 262144;
    const ushort_t* gw1b = w2b  + 262144;
    const ushort_t* ggwb = gw1b + 131072;

    int b = blockIdx.x;
    int tid = threadIdx.x;
    int wave = tid>>6, lane = tid&63;

    __shared__ float pool[11840];
    float* iw    = pool;          // 320   [all]
    float* impd  = pool + 320;    // 1280  [all]
    float* sc    = pool + 1600;   // 1280  [S1-S4]
    float* qkv   = pool + 2880;   // 3840  [S2-S3]
    float* oatt  = pool + 6720;   // 1280  [S3-S4]
    float* h1    = pool + 8000;   // 1280  [S4-S6]
    float* mh    = pool + 2880;   // 5120  [S5-S6] overlays qkv/oatt
    float* sew   = pool + 1600;   // 1280  [S6-S9] overlays sc
    float* ga    = pool + 9280;   // 1280  [S7-S8]
    float* gb_   = pool + 10560;  // 1280  [S7-S8]
    float* goutL = pool + 2880;   // 1280  [S9-S10] overlays mh
    float* tt5   = pool + 4160;   // 1280  [S9]
    __shared__ float att[NHEAD][SEQ][SEQ];
    __shared__ float dyn[SEQ][SEQ];
    __shared__ float gcomb[SEQ][SEQ];
    __shared__ float red[4];

    if (tid < 64){
        #pragma unroll
        for (int k=0;k<5;k++) iw[k*64+tid] = imp_w[k*64+tid];
    }
    __syncthreads();

    // S1: scale (mean over n) + importance dot, per (k, d=tid)
    for (int k=0;k<5;k++){
        const float4* zl = reinterpret_cast<const float4*>(
            out_local + ((size_t)(b*NBANDS+k)*DIM + tid)*NNODE);
        const float* iwk = iw + k*64;
        float s=0.f, di=0.f;
        #pragma unroll
        for (int q=0;q<16;q++){
            float4 v = zl[q];
            s  += v.x + v.y + v.z + v.w;
            di += v.x*iwk[q*4] + v.y*iwk[q*4+1] + v.z*iwk[q*4+2] + v.w*iwk[q*4+3];
        }
        sc[k*DIM+tid]   = s * (1.f/64.f);
        impd[k*DIM+tid] = di;
    }
    __syncthreads();

    // S2: qkv = sc @ qkv_w + b (5 rows concurrently per weight load)
    {
        float a0[5]={0,0,0,0,0}, a1[5]={0,0,0,0,0}, a2[5]={0,0,0,0,0};
        for (int kk=0; kk<DIM; ++kk){
            float w0 = bu2f(qkvb[(size_t)kk*768 + tid]);
            float w1v= bu2f(qkvb[(size_t)kk*768 + 256 + tid]);
            float w2v= bu2f(qkvb[(size_t)kk*768 + 512 + tid]);
            #pragma unroll
            for (int s=0;s<5;s++){
                float xv = sc[s*DIM + kk];
                a0[s] += xv*w0; a1[s] += xv*w1v; a2[s] += xv*w2v;
            }
        }
        float b0 = qkv_bias[tid], b1v = qkv_bias[256+tid], b2v = qkv_bias[512+tid];
        #pragma unroll
        for (int s=0;s<5;s++){
            qkv[s*768 + tid]       = a0[s] + b0;
            qkv[s*768 + 256 + tid] = a1[s] + b1v;
            qkv[s*768 + 512 + tid] = a2[s] + b2v;
        }
    }
    __syncthreads();

    // S3: attention, head = wave
    {
        int h = wave, l = lane;
        for (int i=0;i<5;i++){
            float qv = qkv[i*768 + h*64 + l];
            for (int j=0;j<5;j++){
                float kv = qkv[j*768 + 256 + h*64 + l];
                float p = qv*kv;
                for (int o=32;o>0;o>>=1) p += __shfl_xor(p,o,64);
                if (l==0) att[h][i][j] = p*0.125f;
            }
        }
        __syncthreads();
        if (l==0){
            for (int i=0;i<5;i++){
                float m=-1e30f;
                for (int j=0;j<5;j++) m = fmaxf(m, att[h][i][j]);
                float e[5]; float ssum=0.f;
                for (int j=0;j<5;j++){ e[j]=__expf(att[h][i][j]-m); ssum+=e[j]; }
                for (int j=0;j<5;j++) att[h][i][j]=e[j]/ssum;
            }
        }
        __syncthreads();
        for (int i=0;i<5;i++){
            float acc=0.f;
            for (int j=0;j<5;j++) acc += att[h][i][j]*qkv[j*768 + 512 + h*64 + l];
            oatt[i*DIM + h*64 + l] = acc;
        }
    }
    __syncthreads();

    // S4: proj + residual + LN1
    {
        float pa[5]={0,0,0,0,0};
        for (int dp=0; dp<DIM; ++dp){
            float w = bu2f(owb[(size_t)dp*DIM + tid]);
            #pragma unroll
            for (int s=0;s<5;s++) pa[s] += oatt[s*DIM+dp]*w;
        }
        float obv = ob[tid], g = ln1_g[tid], be = ln1_b[tid];
        for (int s=0;s<5;s++){
            float v = pa[s] + obv + sc[s*DIM+tid];
            float o = block_ln(v, tid, red, g, be);
            h1[s*DIM+tid] = o;
            __syncthreads();
        }
    }

    // S5: mlp1 hidden (gelu)
    {
        float ma[20];
        #pragma unroll
        for (int i=0;i<20;i++) ma[i]=0.f;
        for (int dp=0; dp<DIM; ++dp){
            float w0 = bu2f(w1b[(size_t)dp*1024 + tid]);
            float w1v= bu2f(w1b[(size_t)dp*1024 + 256 + tid]);
            float w2v= bu2f(w1b[(size_t)dp*1024 + 512 + tid]);
            float w3 = bu2f(w1b[(size_t)dp*1024 + 768 + tid]);
            #pragma unroll
            for (int s=0;s<5;s++){
                float xv = h1[s*DIM+dp];
                ma[s*4+0] += xv*w0; ma[s*4+1] += xv*w1v;
                ma[s*4+2] += xv*w2v; ma[s*4+3] += xv*w3;
            }
        }
        float bb[4] = {mb1[tid], mb1[256+tid], mb1[512+tid], mb1[768+tid]};
        #pragma unroll
        for (int s=0;s<5;s++){
            #pragma unroll
            for (int c=0;c<4;c++){
                float v = ma[s*4+c] + bb[c];
                mh[s*1024 + c*256 + tid] = 0.5f*v*(1.f + erff(v*0.70710678118654752f));
            }
        }
    }
    __syncthreads();

    // S6: mlp2 + residual + LN2
    {
        float sa[5]={0,0,0,0,0};
        for (int dp=0; dp<1024; ++dp){
            float w = bu2f(w2b[(size_t)dp*DIM + tid]);
            #pragma unroll
            for (int s=0;s<5;s++) sa[s] += mh[s*1024+dp]*w;
        }
        float bv = mb2[tid], g = ln2_g[tid], be = ln2_b[tid];
        for (int s=0;s<5;s++){
            float v = sa[s] + bv + h1[s*DIM+tid];
            float o = block_ln(v, tid, red, g, be);
            __syncthreads();
            sew[s*DIM+tid] = o;      // overlays sc (dead)
            __syncthreads();
        }
    }

    // S7: gab
    {
        float aA[5]={0,0,0,0,0}, aB[5]={0,0,0,0,0};
        for (int dp=0; dp<DIM; ++dp){
            float wA = bu2f(gw1b[(size_t)dp*DIM + tid]);
            float wB = bu2f(gw1b[(size_t)(DIM+dp)*DIM + tid]);
            #pragma unroll
            for (int s=0;s<5;s++){
                float xv = sew[s*DIM+dp];
                aA[s] += xv*wA; aB[s] += xv*wB;
            }
        }
        float b1v = gb1[tid];
        #pragma unroll
        for (int s=0;s<5;s++){
            ga[s*DIM+tid]  = aA[s] + b1v;
            gb_[s*DIM+tid] = aB[s];
        }
    }
    __syncthreads();

    // S8: global adjacency
    for (int p=wave; p<25; p+=4){
        int i = p/5, j = p%5;
        float acc = 0.f;
        #pragma unroll
        for (int m=0;m<4;m++){
            int dd = lane + m*64;
            float v = ga[i*DIM+dd] + gb_[j*DIM+dd];
            float e = (v>0.f) ? v : (__expf(v)-1.f);
            acc += e * gw2[dd];
        }
        for (int o=32;o>0;o>>=1) acc += __shfl_xor(acc,o,64);
        if (lane==0) dyn[i][j] = acc;
    }
    __syncthreads();
    if (tid < 5){
        int i = tid;
        float sb2 = gb2[0];
        float row[5]; float m=-1e30f;
        for (int j=0;j<5;j++){
            float sg = 1.f/(1.f+__expf(-(dyn[i][j]+sb2)));
            row[j] = gbase[i*5+j] + sg;
            m = fmaxf(m,row[j]);
        }
        float ssum=0.f;
        for (int j=0;j<5;j++){ row[j]=__expf(row[j]-m); ssum+=row[j]; }
        for (int j=0;j<5;j++){
            float c = row[j]/ssum;
            gcomb[i][j] = c;
            out_gadj[((size_t)b*5+i)*5 + j] = c;
        }
    }
    __syncthreads();

    // S9: gmix (all rows) + gout
    {
        #pragma unroll
        for (int k=0;k<5;k++){
            float t = 0.f;
            #pragma unroll
            for (int j=0;j<5;j++) t += gcomb[k][j]*sew[j*DIM+tid];
            tt5[k*DIM+tid] = t;
        }
        __syncthreads();
        float ga5[5]={0,0,0,0,0};
        for (int dp=0; dp<DIM; ++dp){
            float w = bu2f(ggwb[(size_t)dp*DIM + tid]);
            #pragma unroll
            for (int k=0;k<5;k++) ga5[k] += tt5[k*DIM+dp]*w;
        }
        float bv = ggb[tid];
        #pragma unroll
        for (int k=0;k<5;k++) goutL[k*DIM+tid] = ga5[k] + bv;
    }
    __syncthreads();

    // S10: final modulation
    #pragma unroll
    for (int k=0;k<5;k++){
        out0[((size_t)(b*5+k))*DIM + tid] = goutL[k*DIM+tid]*impd[k*DIM+tid] + imp_b[k];
    }
}

extern "C" void kernel_launch(void* const* d_in, const int* in_sizes, int n_in,
                              void* d_out, int out_size, void* d_ws, size_t ws_size,
                              hipStream_t stream)
{
    const float* feature      = (const float*)d_in[0];
    const float* l_adj_w      = (const float*)d_in[1];
    const float* l_sim_w1     = (const float*)d_in[2];
    const float* l_sim_b1     = (const float*)d_in[3];
    const float* l_sim_w2     = (const float*)d_in[4];
    const float* l_sim_b2     = (const float*)d_in[5];
    const float* l_pos_factor = (const float*)d_in[6];
    const float* l_pos_enc    = (const float*)d_in[7];
    const float* l_gcn_w      = (const float*)d_in[8];
    const float* l_gcn_b      = (const float*)d_in[9];
    const float* g_adj_w      = (const float*)d_in[10];
    const float* g_sim_w1     = (const float*)d_in[11];
    const float* g_sim_b1     = (const float*)d_in[12];
    const float* g_sim_w2     = (const float*)d_in[13];
    const float* g_sim_b2     = (const float*)d_in[14];
    const float* g_pos_factor = (const float*)d_in[15];
    const float* g_pos_enc    = (const float*)d_in[16];
    const float* g_gcn_w      = (const float*)d_in[17];
    const float* g_gcn_b      = (const float*)d_in[18];
    const float* qkv_w        = (const float*)d_in[19];
    const float* qkv_b        = (const float*)d_in[20];
    const float* attn_ow      = (const float*)d_in[21];
    const float* attn_ob      = (const float*)d_in[22];
    const float* ln1_g        = (const float*)d_in[23];
    const float* ln1_b        = (const float*)d_in[24];
    const float* ln2_g        = (const float*)d_in[25];
    const float* ln2_b        = (const float*)d_in[26];
    const float* mlp_w1       = (const float*)d_in[27];
    const float* mlp_b1       = (const float*)d_in[28];
    const float* mlp_w2       = (const float*)d_in[29];
    const float* mlp_b2       = (const float*)d_in[30];
    const float* imp_w        = (const float*)d_in[31];
    const float* imp_b        = (const float*)d_in[32];

    float* out0      = (float*)d_out;
    float* out_gadj  = out0 + (size_t)BATCH*NBANDS*DIM;
    float* out_local = out_gadj + (size_t)BATCH*NBANDS*NBANDS;

    const size_t BIG = (size_t)NBANDS*BATCH*NNODE*DIM;           // 1,310,720 elems
    ushort_t* xtb   = (ushort_t*)d_ws;                           // bf16 [k,b,n,d]
    ushort_t* aab   = xtb + BIG;                                 // bf16 a (reused as y)
    ushort_t* bbb   = aab + BIG;                                 // bf16 bp
    ushort_t* xtT   = bbb + BIG;                                 // bf16 [k,b,d,n]
    ushort_t* yb    = aab;
    ushort_t* w1bt  = xtT + BIG;                                 // bf16 [k][512][256]
    ushort_t* gwbt  = w1bt + (size_t)NBANDS*512*DIM;             // bf16 [k][256][256]
    ushort_t* combb = gwbt + (size_t)NBANDS*DIM*DIM;             // bf16 [kb][64][64]
    ushort_t* tailw = combb + (size_t)NBANDS*BATCH*NNODE*NNODE;  // bf16, 983040
    float* fp = (float*)(tailw + 983040);
    float* sbase  = fp; fp += NBANDS*NNODE*NNODE;
    float* gbase  = fp; fp += 32;

    k_head<<<593, 256, 0, stream>>>(l_adj_w, l_pos_enc, l_pos_factor,
                                    g_adj_w, g_pos_enc, g_pos_factor,
                                    sbase, gbase,
                                    l_sim_w1, l_gcn_w, w1bt, gwbt,
                                    feature, xtb, xtT,
                                    qkv_w, attn_ow, mlp_w1, mlp_w2, g_sim_w1, g_gcn_w,
                                    tailw);
    k_ab_mfma<<<NBANDS*BATCH*8, 256, 0, stream>>>(xtb, w1bt, l_sim_b1, aab, bbb);
    k_dyn_comb<<<NBANDS*BATCH*16, 256, 0, stream>>>(aab, bbb, l_sim_w2, l_sim_b2, sbase, combb);
    k_y_mfma<<<NBANDS*BATCH*4, 256, 0, stream>>>(combb, xtT, yb);
    k_gcn_mfma<<<NBANDS*BATCH*4, 256, 0, stream>>>(yb, gwbt, l_gcn_b, out_local);
    k_tail<<<BATCH, 256, 0, stream>>>(out_local, tailw,
                                      qkv_b, attn_ob, ln1_g, ln1_b,
                                      mlp_b1, mlp_b2, ln2_g, ln2_b,
                                      g_sim_b1, g_sim_w2, g_sim_b2, gbase,
                                      g_gcn_b, imp_w, imp_b,
                                      out0, out_gadj);
}

// Round 7
// 240.321 us; speedup vs baseline: 1.4999x; 1.4999x over previous
//
#include <hip/hip_runtime.h>
#include <hip/hip_bf16.h>

#define NBANDS 5
#define BATCH  16
#define DIM    256
#define NNODE  64
#define SEQ    5
#define NHEAD  4
#define DHEAD  64

typedef __hip_bfloat16 bf16;
typedef unsigned short ushort_t;
typedef __attribute__((ext_vector_type(8))) short short8;   // 8 bf16 (4 VGPRs)
typedef __attribute__((ext_vector_type(4))) float float4v;  // 4 fp32 acc

__device__ __forceinline__ float bu2f(ushort_t u){
    bf16 h = *reinterpret_cast<bf16*>(&u);
    return __bfloat162float(h);
}
__device__ __forceinline__ ushort_t f2bu(float x){
    bf16 h = __float2bfloat16(x);
    return *reinterpret_cast<ushort_t*>(&h);
}

// ============ k_head: bases + MFMA weight prep + feature transpose ============
// blocks [0,80):   local sbase, 4 rows/block
// block  80:       global gbase
// blocks [81,321): w1/gw transpose+convert (15 insts x 16 tiles)
// blocks [321,401): feature -> xtb [k,b,n,d] + xtT [k,b,d,n]
__global__ void __launch_bounds__(256) k_head(
    const float* __restrict__ l_adj_w, const float* __restrict__ l_pos_enc,
    const float* __restrict__ l_pf,
    const float* __restrict__ g_adj_w, const float* __restrict__ g_pos_enc,
    const float* __restrict__ g_pf,
    float* __restrict__ sbase, float* __restrict__ gbase,
    const float* __restrict__ w1, const float* __restrict__ gw,
    ushort_t* __restrict__ w1bt, ushort_t* __restrict__ gwbt,
    const float* __restrict__ feat,
    ushort_t* __restrict__ xtb, ushort_t* __restrict__ xtT)
{
    int blk = blockIdx.x;
    int tid = threadIdx.x;
    __shared__ ushort_t tile[64][65];

    if (blk < 80) {
        int r = blk*4 + (tid>>6);
        int k = r >> 6, i = r & 63;
        int t = tid & 63;
        float aw = l_adj_w[(k*NNODE + i)*NNODE + t];
        float pe = l_pos_enc[(k*NNODE + i)*NNODE + t];
        float m1 = aw, m2 = pe;
        for (int o=32;o>0;o>>=1){ m1 = fmaxf(m1, __shfl_xor(m1,o,64)); m2 = fmaxf(m2, __shfl_xor(m2,o,64)); }
        float e1 = __expf(aw-m1), e2 = __expf(pe-m2);
        float s1=e1, s2=e2;
        for (int o=32;o>0;o>>=1){ s1 += __shfl_xor(s1,o,64); s2 += __shfl_xor(s2,o,64); }
        float pf = l_pf[k];
        sbase[(k*NNODE+i)*NNODE + t] = e1/s1 + pf*(e2/s2);
    } else if (blk == 80) {
        if (tid < NBANDS) {
            int i = tid;
            float r1[NBANDS], r2[NBANDS];
            float m1=-1e30f, m2=-1e30f;
            for (int j=0;j<NBANDS;j++){
                r1[j]=g_adj_w[i*NBANDS+j]; r2[j]=g_pos_enc[i*NBANDS+j];
                m1=fmaxf(m1,r1[j]); m2=fmaxf(m2,r2[j]);
            }
            float s1=0.f,s2=0.f;
            for (int j=0;j<NBANDS;j++){ r1[j]=__expf(r1[j]-m1); r2[j]=__expf(r2[j]-m2); s1+=r1[j]; s2+=r2[j]; }
            float pf = g_pf[0];
            for (int j=0;j<NBANDS;j++) gbase[i*NBANDS+j] = r1[j]/s1 + pf*(r2[j]/s2);
        }
    } else if (blk < 321) {
        int idx = blk - 81;
        int inst = idx >> 4;
        int t = idx & 15;
        int r0 = (t>>2)*64, c0 = (t&3)*64;
        const float* src; ushort_t* dst;
        if (inst < 10){
            int k = inst>>1, half = inst&1;
            src = w1  + ((size_t)k*512 + half*256)*256;
            dst = w1bt+ ((size_t)k*512 + half*256)*256;
        } else {
            int k = inst-10;
            src = gw  + (size_t)k*65536;
            dst = gwbt+ (size_t)k*65536;
        }
        int jj = tid & 63, i4 = tid >> 6;
        for (int p=0;p<16;p++){
            int i = p*4 + i4;
            tile[i][jj] = f2bu(src[(size_t)(r0+i)*256 + c0 + jj]);
        }
        __syncthreads();
        for (int p=0;p<16;p++){
            int i = p*4 + i4;
            dst[(size_t)(c0+i)*256 + r0 + jj] = tile[jj][i];
        }
    } else {
        int idx = blk - 321;
        int k = idx / BATCH, b = idx % BATCH;
        const float* src = feat + ((size_t)b*NBANDS*DIM + (size_t)k*DIM)*NNODE; // [D][N]
        ushort_t* dst = xtb + (size_t)(k*BATCH+b)*NNODE*DIM;                    // [N][D]
        ushort_t* dstT = xtT + (size_t)(k*BATCH+b)*DIM*NNODE;                   // [D][N]
        for (int u=0; u<64; ++u){
            int i = u*256 + tid;
            dstT[i] = f2bu(src[i]);
        }
        for (int dt=0; dt<4; ++dt){
            for (int r=0;r<16;r++){
                int dp = r*4 + (tid>>6);
                int n  = tid & 63;
                tile[dp][n] = f2bu(src[(size_t)(dt*64+dp)*NNODE + n]);
            }
            __syncthreads();
            for (int r=0;r<16;r++){
                int n  = r*4 + (tid>>6);
                int dp = tid & 63;
                dst[(size_t)n*DIM + dt*64 + dp] = tile[dp][n];
            }
            __syncthreads();
        }
    }
}

// ---- MFMA a/bp: per band GEMM [1024 x 256] @ [256 x 512] -> aab|bbb bf16 ----
__global__ void __launch_bounds__(256) k_ab_mfma(const ushort_t* __restrict__ xtb,
                        const ushort_t* __restrict__ w1bt, const float* __restrict__ b1,
                        ushort_t* __restrict__ aab, ushort_t* __restrict__ bbb)
{
    int blk = blockIdx.x;                 // 5*16*8
    int kband = blk / (BATCH*8);
    int b = (blk/8) % BATCH;
    int nblk = blk & 7;
    int tid = threadIdx.x;
    int wave = tid>>6, lane = tid&63;
    int c16 = lane & 15, quad = lane >> 4;
    int m0 = wave*16;
    size_t rowbase = (size_t)(kband*BATCH+b)*NNODE;
    const ushort_t* Aptr = xtb + (rowbase + m0 + c16)*DIM + quad*8;
    const ushort_t* Bbase = w1bt + (size_t)kband*512*DIM;
    int ncol0 = nblk*64;
    const ushort_t* Bptr0 = Bbase + (size_t)(ncol0 +  0 + c16)*DIM + quad*8;
    const ushort_t* Bptr1 = Bbase + (size_t)(ncol0 + 16 + c16)*DIM + quad*8;
    const ushort_t* Bptr2 = Bbase + (size_t)(ncol0 + 32 + c16)*DIM + quad*8;
    const ushort_t* Bptr3 = Bbase + (size_t)(ncol0 + 48 + c16)*DIM + quad*8;
    float4v acc0 = {0.f,0.f,0.f,0.f}, acc1 = acc0, acc2 = acc0, acc3 = acc0;
    #pragma unroll
    for (int ks=0; ks<8; ++ks){
        short8 a  = *reinterpret_cast<const short8*>(Aptr  + ks*32);
        short8 b0 = *reinterpret_cast<const short8*>(Bptr0 + ks*32);
        short8 b1v= *reinterpret_cast<const short8*>(Bptr1 + ks*32);
        short8 b2 = *reinterpret_cast<const short8*>(Bptr2 + ks*32);
        short8 b3 = *reinterpret_cast<const short8*>(Bptr3 + ks*32);
        acc0 = __builtin_amdgcn_mfma_f32_16x16x32_bf16(a, b0, acc0, 0,0,0);
        acc1 = __builtin_amdgcn_mfma_f32_16x16x32_bf16(a, b1v, acc1, 0,0,0);
        acc2 = __builtin_amdgcn_mfma_f32_16x16x32_bf16(a, b2, acc2, 0,0,0);
        acc3 = __builtin_amdgcn_mfma_f32_16x16x32_bf16(a, b3, acc3, 0,0,0);
    }
    int half = nblk >> 2;
    int cbase = (nblk & 3)*64;
    ushort_t* dst = half ? bbb : aab;
    float4v accs[4] = {acc0, acc1, acc2, acc3};
    #pragma unroll
    for (int nt=0; nt<4; ++nt){
        int cg = cbase + nt*16 + c16;
        float bias = half ? 0.f : b1[kband*DIM + cg];
        #pragma unroll
        for (int r=0;r<4;r++){
            int m = m0 + quad*4 + r;
            dst[(rowbase + m)*DIM + cg] = f2bu(accs[nt][r] + bias);
        }
    }
}

// ------- dyn+comb: lane j owns pair (i,j); b-tile staged in LDS -------------
__global__ void __launch_bounds__(256) k_dyn_comb(const ushort_t* __restrict__ aab,
                           const ushort_t* __restrict__ bbb,
                           const float* __restrict__ w2, const float* __restrict__ b2arr,
                           const float* __restrict__ sbase,
                           ushort_t* __restrict__ combb)
{
    int blk = blockIdx.x;                     // 5*16*16 blocks, 4 i-rows each
    int k = blk / (BATCH*16);
    int b = (blk / 16) % BATCH;
    int i0 = (blk % 16) * 4;
    int kb = k*BATCH + b;
    __shared__ ushort_t bs[64][260];          // [j][d], pad keeps 8B row align
    __shared__ float arows[4][DIM];
    __shared__ float w2s[DIM];
    int tid = threadIdx.x;
    int wave = tid >> 6, lane = tid & 63;
    // stage b-tile (64x256 bf16, ushort4 per thread x 16)
    const ushort_t* bsrc = bbb + (size_t)kb*NNODE*DIM;
    for (int u=0; u<16; ++u){
        int idx = u*1024 + tid*4;
        int row = idx >> 8, col = idx & 255;
        *reinterpret_cast<ushort4*>(&bs[row][col]) =
            *reinterpret_cast<const ushort4*>(&bsrc[(size_t)row*DIM + col]);
    }
    for (int r=0;r<4;r++) arows[r][tid] = bu2f(aab[((size_t)kb*NNODE + i0 + r)*DIM + tid]);
    w2s[tid] = w2[k*DIM + tid];
    __syncthreads();

    int i = i0 + wave;
    float acc = 0.f;
    #pragma unroll 4
    for (int dd=0; dd<64; ++dd){
        ushort4 bv = *reinterpret_cast<const ushort4*>(&bs[lane][dd*4]);
        float4 av = *reinterpret_cast<const float4*>(&arows[wave][dd*4]);
        float4 wv = *reinterpret_cast<const float4*>(&w2s[dd*4]);
        float v0 = av.x + bu2f(bv.x);
        float v1 = av.y + bu2f(bv.y);
        float v2 = av.z + bu2f(bv.z);
        float v3 = av.w + bu2f(bv.w);
        float e0 = (v0>0.f)? v0 : (__expf(v0)-1.f);
        float e1 = (v1>0.f)? v1 : (__expf(v1)-1.f);
        float e2 = (v2>0.f)? v2 : (__expf(v2)-1.f);
        float e3 = (v3>0.f)? v3 : (__expf(v3)-1.f);
        acc += e0*wv.x + e1*wv.y + e2*wv.z + e3*wv.w;
    }
    // sigmoid + base + wave softmax (lane = j)
    float sb2 = b2arr[k];
    float sg = 1.f/(1.f + __expf(-(acc + sb2)));
    float val = sbase[(k*NNODE + i)*NNODE + lane] + sg;
    float m = val;
    for (int o=32;o>0;o>>=1) m = fmaxf(m, __shfl_xor(m,o,64));
    float e = __expf(val - m);
    float s = e;
    for (int o=32;o>0;o>>=1) s += __shfl_xor(s,o,64);
    combb[((size_t)kb*NNODE + i)*NNODE + lane] = f2bu(e/s);
}

// ---- MFMA y: per (k,b) GEMM [64 x 64] @ [64 x 256] -> yb bf16 [kb][n][d] ----
__global__ void __launch_bounds__(256) k_y_mfma(const ushort_t* __restrict__ combb,
                       const ushort_t* __restrict__ xtT,
                       ushort_t* __restrict__ yb)
{
    int blk = blockIdx.x;                 // 5*16*4
    int kband = blk / (BATCH*4);
    int b = (blk/4) % BATCH;
    int nblk = blk & 3;
    int tid = threadIdx.x;
    int wave = tid>>6, lane = tid&63;
    int c16 = lane & 15, quad = lane >> 4;
    int m0 = wave*16;
    int kb = kband*BATCH + b;
    const ushort_t* Aptr = combb + ((size_t)kb*NNODE + m0 + c16)*NNODE + quad*8;  // [n][j]
    const ushort_t* Bbase = xtT + (size_t)kb*DIM*NNODE;                            // [d][j]
    int ncol0 = nblk*64;
    const ushort_t* Bptr0 = Bbase + (size_t)(ncol0 +  0 + c16)*NNODE + quad*8;
    const ushort_t* Bptr1 = Bbase + (size_t)(ncol0 + 16 + c16)*NNODE + quad*8;
    const ushort_t* Bptr2 = Bbase + (size_t)(ncol0 + 32 + c16)*NNODE + quad*8;
    const ushort_t* Bptr3 = Bbase + (size_t)(ncol0 + 48 + c16)*NNODE + quad*8;
    float4v acc0 = {0.f,0.f,0.f,0.f}, acc1 = acc0, acc2 = acc0, acc3 = acc0;
    #pragma unroll
    for (int ks=0; ks<2; ++ks){
        short8 a  = *reinterpret_cast<const short8*>(Aptr  + ks*32);
        short8 b0 = *reinterpret_cast<const short8*>(Bptr0 + ks*32);
        short8 b1v= *reinterpret_cast<const short8*>(Bptr1 + ks*32);
        short8 b2 = *reinterpret_cast<const short8*>(Bptr2 + ks*32);
        short8 b3 = *reinterpret_cast<const short8*>(Bptr3 + ks*32);
        acc0 = __builtin_amdgcn_mfma_f32_16x16x32_bf16(a, b0, acc0, 0,0,0);
        acc1 = __builtin_amdgcn_mfma_f32_16x16x32_bf16(a, b1v, acc1, 0,0,0);
        acc2 = __builtin_amdgcn_mfma_f32_16x16x32_bf16(a, b2, acc2, 0,0,0);
        acc3 = __builtin_amdgcn_mfma_f32_16x16x32_bf16(a, b3, acc3, 0,0,0);
    }
    size_t rowbase = (size_t)kb*NNODE;
    float4v accs[4] = {acc0, acc1, acc2, acc3};
    #pragma unroll
    for (int nt=0; nt<4; ++nt){
        int cg = ncol0 + nt*16 + c16;
        #pragma unroll
        for (int r=0;r<4;r++){
            int m = m0 + quad*4 + r;
            yb[(rowbase + m)*DIM + cg] = f2bu(accs[nt][r]);
        }
    }
}

// ---- MFMA gcn: [64 x 256] @ [256 x 256] + bias -> out_local f32 [b,k,d,n] ----
__global__ void __launch_bounds__(256) k_gcn_mfma(const ushort_t* __restrict__ yb,
                         const ushort_t* __restrict__ gwbt, const float* __restrict__ gb,
                         float* __restrict__ out_local)
{
    int blk = blockIdx.x;                 // 5*16*4
    int kband = blk / (BATCH*4);
    int b = (blk/4) % BATCH;
    int nblk = blk & 3;
    int tid = threadIdx.x;
    int wave = tid>>6, lane = tid&63;
    int c16 = lane & 15, quad = lane >> 4;
    int m0 = wave*16;
    int kb = kband*BATCH + b;
    const ushort_t* Aptr = yb + ((size_t)kb*NNODE + m0 + c16)*DIM + quad*8;  // [n][d]
    const ushort_t* Bbase = gwbt + (size_t)kband*DIM*DIM;                    // [col][kk]
    int ncol0 = nblk*64;
    const ushort_t* Bptr0 = Bbase + (size_t)(ncol0 +  0 + c16)*DIM + quad*8;
    const ushort_t* Bptr1 = Bbase + (size_t)(ncol0 + 16 + c16)*DIM + quad*8;
    const ushort_t* Bptr2 = Bbase + (size_t)(ncol0 + 32 + c16)*DIM + quad*8;
    const ushort_t* Bptr3 = Bbase + (size_t)(ncol0 + 48 + c16)*DIM + quad*8;
    float4v acc0 = {0.f,0.f,0.f,0.f}, acc1 = acc0, acc2 = acc0, acc3 = acc0;
    #pragma unroll
    for (int ks=0; ks<8; ++ks){
        short8 a  = *reinterpret_cast<const short8*>(Aptr  + ks*32);
        short8 b0 = *reinterpret_cast<const short8*>(Bptr0 + ks*32);
        short8 b1v= *reinterpret_cast<const short8*>(Bptr1 + ks*32);
        short8 b2 = *reinterpret_cast<const short8*>(Bptr2 + ks*32);
        short8 b3 = *reinterpret_cast<const short8*>(Bptr3 + ks*32);
        acc0 = __builtin_amdgcn_mfma_f32_16x16x32_bf16(a, b0, acc0, 0,0,0);
        acc1 = __builtin_amdgcn_mfma_f32_16x16x32_bf16(a, b1v, acc1, 0,0,0);
        acc2 = __builtin_amdgcn_mfma_f32_16x16x32_bf16(a, b2, acc2, 0,0,0);
        acc3 = __builtin_amdgcn_mfma_f32_16x16x32_bf16(a, b3, acc3, 0,0,0);
    }
    float4v accs[4] = {acc0, acc1, acc2, acc3};
    #pragma unroll
    for (int nt=0; nt<4; ++nt){
        int cg = ncol0 + nt*16 + c16;
        float bias = gb[kband*DIM + cg];
        float4 v = make_float4(accs[nt][0]+bias, accs[nt][1]+bias, accs[nt][2]+bias, accs[nt][3]+bias);
        float* dst = out_local + ((size_t)(b*NBANDS + kband)*DIM + cg)*NNODE + m0 + quad*4;
        *reinterpret_cast<float4*>(dst) = v;
    }
}

// ---------------- scale + importance dot ------------------------------------
__global__ void k_scale2(const float* __restrict__ out_local, const float* __restrict__ imp_w,
                         float* __restrict__ scalew, float* __restrict__ impw)
{
    int k = blockIdx.x / BATCH, b = blockIdx.x % BATCH;
    int d = threadIdx.x;
    __shared__ float iw[NNODE];
    if (d < NNODE) iw[d] = imp_w[k*NNODE + d];
    __syncthreads();
    const float4* zl = reinterpret_cast<const float4*>(out_local + ((size_t)(b*NBANDS + k)*DIM + d)*NNODE);
    float s = 0.f, di = 0.f;
    #pragma unroll
    for (int q=0;q<16;++q){
        float4 v = zl[q];
        s  += v.x + v.y + v.z + v.w;
        di += v.x*iw[q*4] + v.y*iw[q*4+1] + v.z*iw[q*4+2] + v.w*iw[q*4+3];
    }
    scalew[((size_t)b*SEQ + k)*DIM + d] = s * (1.f/64.f);
    impw[((size_t)b*SEQ + k)*DIM + d]   = di;
}

// ---- generic sliced GEMV: out[row][n] = act(bias[n] + sum_k x[row][k] w[k][n]) ----
template<int COLS, int SLICES>
__global__ void __launch_bounds__(256) k_gemv(const float* __restrict__ x, const float* __restrict__ w,
                       const float* __restrict__ bias, float* __restrict__ out,
                       int K, int N, int act)
{
    int chunks = N / COLS;
    int row = blockIdx.x / chunks;
    int n0 = (blockIdx.x % chunks) * COLS;
    int c = threadIdx.x % COLS, s = threadIdx.x / COLS;
    __shared__ float xs[1024];
    __shared__ float part[SLICES][COLS];
    for (int i = threadIdx.x; i < K; i += 256) xs[i] = x[(size_t)row*K + i];
    __syncthreads();
    int klen = K / SLICES;
    const float* wp = w + (size_t)(s*klen)*N + n0 + c;
    const float* xp = xs + s*klen;
    float acc = 0.f;
    #pragma unroll 8
    for (int i = 0; i < klen; ++i) acc += xp[i] * wp[(size_t)i*N];
    part[s][c] = acc;
    __syncthreads();
    if (s == 0){
        float v = bias[n0+c];
        #pragma unroll
        for (int q=0;q<SLICES;q++) v += part[q][c];
        if (act) v = 0.5f*v*(1.f + erff(v*0.70710678118654752f));
        out[(size_t)row*N + n0 + c] = v;
    }
}

// ---------------- MHA core: scores, softmax, att@v -> o_ws ------------------
__global__ void k_attn(const float* __restrict__ qkvw, float* __restrict__ ows)
{
    int b = blockIdx.x;
    int tid = threadIdx.x;
    int h = tid >> 6, l = tid & 63;
    __shared__ float att[NHEAD][SEQ][SEQ];
    const float* base = qkvw + (size_t)b*SEQ*3*DIM;
    for (int i=0;i<SEQ;i++){
        float qv = base[(size_t)i*3*DIM + h*DHEAD + l];
        for (int j=0;j<SEQ;j++){
            float kv = base[(size_t)j*3*DIM + DIM + h*DHEAD + l];
            float p = qv * kv;
            for (int o=32;o>0;o>>=1) p += __shfl_xor(p,o,64);
            if (l==0) att[h][i][j] = p * 0.125f;
        }
    }
    __syncthreads();
    if (l == 0){
        for (int i=0;i<SEQ;i++){
            float m=-1e30f;
            for (int j=0;j<SEQ;j++) m = fmaxf(m, att[h][i][j]);
            float e[SEQ]; float s=0.f;
            for (int j=0;j<SEQ;j++){ e[j] = __expf(att[h][i][j]-m); s+=e[j]; }
            for (int j=0;j<SEQ;j++) att[h][i][j] = e[j]/s;
        }
    }
    __syncthreads();
    for (int i=0;i<SEQ;i++){
        float acc=0.f;
        for (int j=0;j<SEQ;j++) acc += att[h][i][j] * base[(size_t)j*3*DIM + 2*DIM + h*DHEAD + l];
        ows[((size_t)b*SEQ + i)*DIM + h*DHEAD + l] = acc;
    }
}

// ---------------- block LayerNorm over 256 elems ----------------------------
__device__ __forceinline__ float block_ln(float v, int tid, float* red, float g, float bln)
{
    float s = v;
    for (int o=32;o>0;o>>=1) s += __shfl_xor(s,o,64);
    int wave = tid>>6, lane = tid&63;
    if (lane==0) red[wave] = s;
    __syncthreads();
    float mean = (red[0]+red[1]+red[2]+red[3]) * (1.f/DIM);
    float c = v - mean;
    float q = c*c;
    for (int o=32;o>0;o>>=1) q += __shfl_xor(q,o,64);
    __syncthreads();
    if (lane==0) red[wave] = q;
    __syncthreads();
    float var = (red[0]+red[1]+red[2]+red[3]) * (1.f/DIM);
    return c * rsqrtf(var + 1e-5f) * g + bln;
}

// ---- mlp1 with fused LN1 prologue: h1 = LN(proj+scale); out = gelu(h1@w1+b1) ----
__global__ void __launch_bounds__(256) k_mlp1_ln(const float* __restrict__ projw,
                         const float* __restrict__ scalew,
                         const float* __restrict__ ln1_g, const float* __restrict__ ln1_b,
                         const float* __restrict__ w1, const float* __restrict__ b1,
                         float* __restrict__ h1w, float* __restrict__ mhw)
{
    int row = blockIdx.x / 16;
    int n0 = (blockIdx.x % 16) * 64;
    int tid = threadIdx.x;
    __shared__ float xs[DIM];
    __shared__ float red[4];
    __shared__ float part[4][64];
    float v = projw[(size_t)row*DIM + tid] + scalew[(size_t)row*DIM + tid];
    float h = block_ln(v, tid, red, ln1_g[tid], ln1_b[tid]);
    xs[tid] = h;
    if ((blockIdx.x % 16) == 0) h1w[(size_t)row*DIM + tid] = h;
    __syncthreads();
    int c = tid & 63, s = tid >> 6;
    const float* wp = w1 + (size_t)(s*64)*1024 + n0 + c;
    const float* xp = xs + s*64;
    float acc = 0.f;
    #pragma unroll 8
    for (int i=0;i<64;++i) acc += xp[i] * wp[(size_t)i*1024];
    part[s][c] = acc;
    __syncthreads();
    if (s == 0){
        float o = b1[n0+c] + part[0][c] + part[1][c] + part[2][c] + part[3][c];
        o = 0.5f*o*(1.f + erff(o*0.70710678118654752f));
        mhw[(size_t)row*1024 + n0 + c] = o;
    }
}

// ---- gab with fused LN2 prologue: sew = LN(m2+h1); ga/gb = sew @ w1 halves ----
__global__ void __launch_bounds__(256) k_gab_ln(const float* __restrict__ m2w,
                        const float* __restrict__ h1w,
                        const float* __restrict__ ln2_g, const float* __restrict__ ln2_b,
                        const float* __restrict__ gw1, const float* __restrict__ gb1,
                        float* __restrict__ sew, float* __restrict__ gaw, float* __restrict__ gbw)
{
    int row = blockIdx.x / 4;
    int n0 = (blockIdx.x % 4) * 64;
    int tid = threadIdx.x;
    __shared__ float xs[DIM];
    __shared__ float red[4];
    __shared__ float partA[4][64];
    __shared__ float partB[4][64];
    float v = m2w[(size_t)row*DIM + tid] + h1w[(size_t)row*DIM + tid];
    float h = block_ln(v, tid, red, ln2_g[tid], ln2_b[tid]);
    xs[tid] = h;
    if ((blockIdx.x % 4) == 0) sew[(size_t)row*DIM + tid] = h;
    __syncthreads();
    int c = tid & 63, s = tid >> 6;
    const float* wpA = gw1 + (size_t)(s*64)*DIM + n0 + c;
    const float* wpB = wpA + (size_t)DIM*DIM;
    const float* xp = xs + s*64;
    float aA = 0.f, aB = 0.f;
    #pragma unroll 8
    for (int i=0;i<64;++i){
        float xv = xp[i];
        aA += xv * wpA[(size_t)i*DIM];
        aB += xv * wpB[(size_t)i*DIM];
    }
    partA[s][c] = aA;
    partB[s][c] = aB;
    __syncthreads();
    if (s == 0){
        gaw[(size_t)row*DIM + n0 + c] = gb1[n0+c] + partA[0][c]+partA[1][c]+partA[2][c]+partA[3][c];
        gbw[(size_t)row*DIM + n0 + c] = partB[0][c]+partB[1][c]+partB[2][c]+partB[3][c];
    }
}

// ---------------- global adj: dyn, comb softmax -> gcomb ws + f32 out -------
__global__ void k_gadj(const float* __restrict__ gaw, const float* __restrict__ gbw,
                       const float* __restrict__ gw2, const float* __restrict__ gb2,
                       const float* __restrict__ gbase,
                       float* __restrict__ gcombw, float* __restrict__ out_gadj)
{
    int b = blockIdx.x;
    int tid = threadIdx.x;
    int wave = tid>>6, lane = tid&63;
    __shared__ float dyn[SEQ][SEQ];
    __shared__ float w2s[DIM];
    w2s[tid] = gw2[tid];
    __syncthreads();
    for (int p = wave; p < SEQ*SEQ; p += 4){
        int i = p / SEQ, j = p % SEQ;
        const float* gar = gaw + ((size_t)b*SEQ+i)*DIM;
        const float* gbr = gbw + ((size_t)b*SEQ+j)*DIM;
        float acc = 0.f;
        #pragma unroll
        for (int m=0;m<4;m++){
            int dd = lane + m*64;
            float v = gar[dd] + gbr[dd];
            float e = (v>0.f) ? v : (__expf(v)-1.f);
            acc += e * w2s[dd];
        }
        for (int o=32;o>0;o>>=1) acc += __shfl_xor(acc,o,64);
        if (lane==0) dyn[i][j] = acc;
    }
    __syncthreads();
    if (tid < SEQ){
        int i = tid;
        float sb2 = gb2[0];
        float row[SEQ]; float m=-1e30f;
        for (int j=0;j<SEQ;j++){
            float sg = 1.f/(1.f+__expf(-(dyn[i][j]+sb2)));
            row[j] = gbase[i*SEQ+j] + sg;
            m = fmaxf(m,row[j]);
        }
        float ssum=0.f;
        for (int j=0;j<SEQ;j++){ row[j]=__expf(row[j]-m); ssum+=row[j]; }
        for (int j=0;j<SEQ;j++){
            float c = row[j]/ssum;
            gcombw[((size_t)b*SEQ+i)*SEQ + j] = c;
            out_gadj[((size_t)b*SEQ+i)*SEQ + j] = c;
        }
    }
}

// ---- gout with fused gmix prologue: trow = gcomb@sew; out = trow@ggw + b ----
__global__ void __launch_bounds__(256) k_gout_mix(const float* __restrict__ gcombw,
                         const float* __restrict__ sew,
                         const float* __restrict__ ggw, const float* __restrict__ ggb,
                         float* __restrict__ goutw)
{
    int row = blockIdx.x / 4;            // b*SEQ + k
    int n0 = (blockIdx.x % 4) * 64;
    int b = row / SEQ;
    int tid = threadIdx.x;
    __shared__ float xs[DIM];
    __shared__ float part[4][64];
    float t = 0.f;
    #pragma unroll
    for (int j=0;j<SEQ;j++) t += gcombw[row*SEQ + j] * sew[((size_t)b*SEQ + j)*DIM + tid];
    xs[tid] = t;
    __syncthreads();
    int c = tid & 63, s = tid >> 6;
    const float* wp = ggw + (size_t)(s*64)*DIM + n0 + c;
    const float* xp = xs + s*64;
    float acc = 0.f;
    #pragma unroll 8
    for (int i=0;i<64;++i) acc += xp[i] * wp[(size_t)i*DIM];
    part[s][c] = acc;
    __syncthreads();
    if (s == 0){
        goutw[(size_t)row*DIM + n0 + c] = ggb[n0+c] + part[0][c]+part[1][c]+part[2][c]+part[3][c];
    }
}

// ------- final: out0 = gout * impd + imp_b ----------------------------------
__global__ void k_final(const float* __restrict__ impw, const float* __restrict__ goutw,
                        const float* __restrict__ imp_b, float* __restrict__ out0)
{
    int row = blockIdx.x;      // b*SEQ + k
    int k = row % NBANDS;
    int d = threadIdx.x;
    out0[(size_t)row*DIM + d] = goutw[(size_t)row*DIM + d] * impw[(size_t)row*DIM + d] + imp_b[k];
}

extern "C" void kernel_launch(void* const* d_in, const int* in_sizes, int n_in,
                              void* d_out, int out_size, void* d_ws, size_t ws_size,
                              hipStream_t stream)
{
    const float* feature      = (const float*)d_in[0];
    const float* l_adj_w      = (const float*)d_in[1];
    const float* l_sim_w1     = (const float*)d_in[2];
    const float* l_sim_b1     = (const float*)d_in[3];
    const float* l_sim_w2     = (const float*)d_in[4];
    const float* l_sim_b2     = (const float*)d_in[5];
    const float* l_pos_factor = (const float*)d_in[6];
    const float* l_pos_enc    = (const float*)d_in[7];
    const float* l_gcn_w      = (const float*)d_in[8];
    const float* l_gcn_b      = (const float*)d_in[9];
    const float* g_adj_w      = (const float*)d_in[10];
    const float* g_sim_w1     = (const float*)d_in[11];
    const float* g_sim_b1     = (const float*)d_in[12];
    const float* g_sim_w2     = (const float*)d_in[13];
    const float* g_sim_b2     = (const float*)d_in[14];
    const float* g_pos_factor = (const float*)d_in[15];
    const float* g_pos_enc    = (const float*)d_in[16];
    const float* g_gcn_w      = (const float*)d_in[17];
    const float* g_gcn_b      = (const float*)d_in[18];
    const float* qkv_w        = (const float*)d_in[19];
    const float* qkv_b        = (const float*)d_in[20];
    const float* attn_ow      = (const float*)d_in[21];
    const float* attn_ob      = (const float*)d_in[22];
    const float* ln1_g        = (const float*)d_in[23];
    const float* ln1_b        = (const float*)d_in[24];
    const float* ln2_g        = (const float*)d_in[25];
    const float* ln2_b        = (const float*)d_in[26];
    const float* mlp_w1       = (const float*)d_in[27];
    const float* mlp_b1       = (const float*)d_in[28];
    const float* mlp_w2       = (const float*)d_in[29];
    const float* mlp_b2       = (const float*)d_in[30];
    const float* imp_w        = (const float*)d_in[31];
    const float* imp_b        = (const float*)d_in[32];

    float* out0      = (float*)d_out;
    float* out_gadj  = out0 + (size_t)BATCH*NBANDS*DIM;
    float* out_local = out_gadj + (size_t)BATCH*NBANDS*NBANDS;

    const size_t BIG = (size_t)NBANDS*BATCH*NNODE*DIM;           // 1,310,720 elems
    ushort_t* xtb   = (ushort_t*)d_ws;                           // bf16 [k,b,n,d]
    ushort_t* aab   = xtb + BIG;                                 // bf16 a (reused as y)
    ushort_t* bbb   = aab + BIG;                                 // bf16 bp
    ushort_t* xtT   = bbb + BIG;                                 // bf16 [k,b,d,n]
    ushort_t* yb    = aab;
    ushort_t* w1bt  = xtT + BIG;                                 // bf16 [k][512][256]
    ushort_t* gwbt  = w1bt + (size_t)NBANDS*512*DIM;             // bf16 [k][256][256]
    ushort_t* combb = gwbt + (size_t)NBANDS*DIM*DIM;             // bf16 [kb][64][64]
    float* fp = (float*)(combb + (size_t)NBANDS*BATCH*NNODE*NNODE);
    float* sbase  = fp; fp += NBANDS*NNODE*NNODE;
    float* gbase  = fp; fp += 32;
    float* scalew = fp; fp += BATCH*SEQ*DIM;
    float* impw   = fp; fp += BATCH*SEQ*DIM;
    float* qkvw   = fp; fp += BATCH*SEQ*3*DIM;
    float* ows    = fp; fp += BATCH*SEQ*DIM;
    float* projw  = fp; fp += BATCH*SEQ*DIM;
    float* h1w    = fp; fp += BATCH*SEQ*DIM;
    float* mhw    = fp; fp += BATCH*SEQ*4*DIM;
    float* m2w    = fp; fp += BATCH*SEQ*DIM;
    float* sew    = fp; fp += BATCH*SEQ*DIM;
    float* gaw    = fp; fp += BATCH*SEQ*DIM;
    float* gbw    = fp; fp += BATCH*SEQ*DIM;
    float* gcombw = fp; fp += 512;
    float* goutw  = fp; fp += BATCH*SEQ*DIM;

    const int ROWS = BATCH*SEQ;   // 80

    k_head<<<401, 256, 0, stream>>>(l_adj_w, l_pos_enc, l_pos_factor,
                                    g_adj_w, g_pos_enc, g_pos_factor,
                                    sbase, gbase,
                                    l_sim_w1, l_gcn_w, w1bt, gwbt,
                                    feature, xtb, xtT);
    k_ab_mfma<<<NBANDS*BATCH*8, 256, 0, stream>>>(xtb, w1bt, l_sim_b1, aab, bbb);
    k_dyn_comb<<<NBANDS*BATCH*16, 256, 0, stream>>>(aab, bbb, l_sim_w2, l_sim_b2, sbase, combb);
    k_y_mfma<<<NBANDS*BATCH*4, 256, 0, stream>>>(combb, xtT, yb);
    k_gcn_mfma<<<NBANDS*BATCH*4, 256, 0, stream>>>(yb, gwbt, l_gcn_b, out_local);
    k_scale2<<<NBANDS*BATCH, 256, 0, stream>>>(out_local, imp_w, scalew, impw);
    k_gemv<64,4><<<ROWS*12, 256, 0, stream>>>(scalew, qkv_w, qkv_b, qkvw, 256, 768, 0);
    k_attn<<<BATCH, 256, 0, stream>>>(qkvw, ows);
    k_gemv<64,4><<<ROWS*4, 256, 0, stream>>>(ows, attn_ow, attn_ob, projw, 256, 256, 0);
    k_mlp1_ln<<<ROWS*16, 256, 0, stream>>>(projw, scalew, ln1_g, ln1_b, mlp_w1, mlp_b1, h1w, mhw);
    k_gemv<32,8><<<ROWS*8, 256, 0, stream>>>(mhw, mlp_w2, mlp_b2, m2w, 1024, 256, 0);
    k_gab_ln<<<ROWS*4, 256, 0, stream>>>(m2w, h1w, ln2_g, ln2_b, g_sim_w1, g_sim_b1, sew, gaw, gbw);
    k_gadj<<<BATCH, 256, 0, stream>>>(gaw, gbw, g_sim_w2, g_sim_b2, gbase, gcombw, out_gadj);
    k_gout_mix<<<ROWS*4, 256, 0, stream>>>(gcombw, sew, g_gcn_w, g_gcn_b, goutw);
    k_final<<<ROWS, 256, 0, stream>>>(impw, goutw, imp_b, out0);
}

// Round 8
// 219.377 us; speedup vs baseline: 1.6431x; 1.0955x over previous
//
#include <hip/hip_runtime.h>
#include <hip/hip_bf16.h>

#define NBANDS 5
#define BATCH  16
#define DIM    256
#define NNODE  64
#define SEQ    5
#define NHEAD  4
#define DHEAD  64

typedef __hip_bfloat16 bf16;
typedef unsigned short ushort_t;
typedef __attribute__((ext_vector_type(8))) short short8;   // 8 bf16 (4 VGPRs)
typedef __attribute__((ext_vector_type(4))) float float4v;  // 4 fp32 acc

__device__ __forceinline__ float bu2f(ushort_t u){
    bf16 h = *reinterpret_cast<bf16*>(&u);
    return __bfloat162float(h);
}
__device__ __forceinline__ ushort_t f2bu(float x){
    bf16 h = __float2bfloat16(x);
    return *reinterpret_cast<ushort_t*>(&h);
}

// ============ k_head: bases + MFMA weight prep + feature transpose ============
// blocks [0,80):   local sbase, 4 rows/block
// block  80:       global gbase
// blocks [81,321): w1/gw transpose+convert (15 insts x 16 tiles)
// blocks [321,641): feature -> xtb + xtT, one (k,b,dt) quarter per block
__global__ void __launch_bounds__(256) k_head(
    const float* __restrict__ l_adj_w, const float* __restrict__ l_pos_enc,
    const float* __restrict__ l_pf,
    const float* __restrict__ g_adj_w, const float* __restrict__ g_pos_enc,
    const float* __restrict__ g_pf,
    float* __restrict__ sbase, float* __restrict__ gbase,
    const float* __restrict__ w1, const float* __restrict__ gw,
    ushort_t* __restrict__ w1bt, ushort_t* __restrict__ gwbt,
    const float* __restrict__ feat,
    ushort_t* __restrict__ xtb, ushort_t* __restrict__ xtT)
{
    int blk = blockIdx.x;
    int tid = threadIdx.x;
    __shared__ ushort_t tile[64][65];

    if (blk < 80) {
        int r = blk*4 + (tid>>6);
        int k = r >> 6, i = r & 63;
        int t = tid & 63;
        float aw = l_adj_w[(k*NNODE + i)*NNODE + t];
        float pe = l_pos_enc[(k*NNODE + i)*NNODE + t];
        float m1 = aw, m2 = pe;
        for (int o=32;o>0;o>>=1){ m1 = fmaxf(m1, __shfl_xor(m1,o,64)); m2 = fmaxf(m2, __shfl_xor(m2,o,64)); }
        float e1 = __expf(aw-m1), e2 = __expf(pe-m2);
        float s1=e1, s2=e2;
        for (int o=32;o>0;o>>=1){ s1 += __shfl_xor(s1,o,64); s2 += __shfl_xor(s2,o,64); }
        float pf = l_pf[k];
        sbase[(k*NNODE+i)*NNODE + t] = e1/s1 + pf*(e2/s2);
    } else if (blk == 80) {
        if (tid < NBANDS) {
            int i = tid;
            float r1[NBANDS], r2[NBANDS];
            float m1=-1e30f, m2=-1e30f;
            for (int j=0;j<NBANDS;j++){
                r1[j]=g_adj_w[i*NBANDS+j]; r2[j]=g_pos_enc[i*NBANDS+j];
                m1=fmaxf(m1,r1[j]); m2=fmaxf(m2,r2[j]);
            }
            float s1=0.f,s2=0.f;
            for (int j=0;j<NBANDS;j++){ r1[j]=__expf(r1[j]-m1); r2[j]=__expf(r2[j]-m2); s1+=r1[j]; s2+=r2[j]; }
            float pf = g_pf[0];
            for (int j=0;j<NBANDS;j++) gbase[i*NBANDS+j] = r1[j]/s1 + pf*(r2[j]/s2);
        }
    } else if (blk < 321) {
        int idx = blk - 81;
        int inst = idx >> 4;
        int t = idx & 15;
        int r0 = (t>>2)*64, c0 = (t&3)*64;
        const float* src; ushort_t* dst;
        if (inst < 10){
            int k = inst>>1, half = inst&1;
            src = w1  + ((size_t)k*512 + half*256)*256;
            dst = w1bt+ ((size_t)k*512 + half*256)*256;
        } else {
            int k = inst-10;
            src = gw  + (size_t)k*65536;
            dst = gwbt+ (size_t)k*65536;
        }
        int jj = tid & 63, i4 = tid >> 6;
        for (int p=0;p<16;p++){
            int i = p*4 + i4;
            tile[i][jj] = f2bu(src[(size_t)(r0+i)*256 + c0 + jj]);
        }
        __syncthreads();
        for (int p=0;p<16;p++){
            int i = p*4 + i4;
            dst[(size_t)(c0+i)*256 + r0 + jj] = tile[jj][i];
        }
    } else {
        int idx = blk - 321;                   // (k,b,dt)
        int k = idx >> 6;
        int b = (idx >> 2) & 15;
        int dt = idx & 3;
        const float* src = feat + ((size_t)b*NBANDS*DIM + (size_t)k*DIM)*NNODE; // [D][N]
        ushort_t* dst = xtb + (size_t)(k*BATCH+b)*NNODE*DIM;                    // [N][D]
        ushort_t* dstT = xtT + (size_t)(k*BATCH+b)*DIM*NNODE;                   // [D][N]
        for (int u=0; u<16; ++u){
            int i = dt*4096 + u*256 + tid;
            dstT[i] = f2bu(src[i]);
        }
        for (int r=0;r<16;r++){
            int dp = r*4 + (tid>>6);
            int n  = tid & 63;
            tile[dp][n] = f2bu(src[(size_t)(dt*64+dp)*NNODE + n]);
        }
        __syncthreads();
        for (int r=0;r<16;r++){
            int n  = r*4 + (tid>>6);
            int dp = tid & 63;
            dst[(size_t)n*DIM + dt*64 + dp] = tile[dp][n];
        }
    }
}

// ---- MFMA a/bp: per band GEMM [1024 x 256] @ [256 x 512] -> aab|bbb bf16 ----
__global__ void __launch_bounds__(256) k_ab_mfma(const ushort_t* __restrict__ xtb,
                        const ushort_t* __restrict__ w1bt, const float* __restrict__ b1,
                        ushort_t* __restrict__ aab, ushort_t* __restrict__ bbb)
{
    int blk = blockIdx.x;                 // 5*16*8
    int kband = blk / (BATCH*8);
    int b = (blk/8) % BATCH;
    int nblk = blk & 7;
    int tid = threadIdx.x;
    int wave = tid>>6, lane = tid&63;
    int c16 = lane & 15, quad = lane >> 4;
    int m0 = wave*16;
    size_t rowbase = (size_t)(kband*BATCH+b)*NNODE;
    const ushort_t* Aptr = xtb + (rowbase + m0 + c16)*DIM + quad*8;
    const ushort_t* Bbase = w1bt + (size_t)kband*512*DIM;
    int ncol0 = nblk*64;
    const ushort_t* Bptr0 = Bbase + (size_t)(ncol0 +  0 + c16)*DIM + quad*8;
    const ushort_t* Bptr1 = Bbase + (size_t)(ncol0 + 16 + c16)*DIM + quad*8;
    const ushort_t* Bptr2 = Bbase + (size_t)(ncol0 + 32 + c16)*DIM + quad*8;
    const ushort_t* Bptr3 = Bbase + (size_t)(ncol0 + 48 + c16)*DIM + quad*8;
    float4v acc0 = {0.f,0.f,0.f,0.f}, acc1 = acc0, acc2 = acc0, acc3 = acc0;
    #pragma unroll
    for (int ks=0; ks<8; ++ks){
        short8 a  = *reinterpret_cast<const short8*>(Aptr  + ks*32);
        short8 b0 = *reinterpret_cast<const short8*>(Bptr0 + ks*32);
        short8 b1v= *reinterpret_cast<const short8*>(Bptr1 + ks*32);
        short8 b2 = *reinterpret_cast<const short8*>(Bptr2 + ks*32);
        short8 b3 = *reinterpret_cast<const short8*>(Bptr3 + ks*32);
        acc0 = __builtin_amdgcn_mfma_f32_16x16x32_bf16(a, b0, acc0, 0,0,0);
        acc1 = __builtin_amdgcn_mfma_f32_16x16x32_bf16(a, b1v, acc1, 0,0,0);
        acc2 = __builtin_amdgcn_mfma_f32_16x16x32_bf16(a, b2, acc2, 0,0,0);
        acc3 = __builtin_amdgcn_mfma_f32_16x16x32_bf16(a, b3, acc3, 0,0,0);
    }
    int half = nblk >> 2;
    int cbase = (nblk & 3)*64;
    ushort_t* dst = half ? bbb : aab;
    float4v accs[4] = {acc0, acc1, acc2, acc3};
    #pragma unroll
    for (int nt=0; nt<4; ++nt){
        int cg = cbase + nt*16 + c16;
        float bias = half ? 0.f : b1[kband*DIM + cg];
        #pragma unroll
        for (int r=0;r<4;r++){
            int m = m0 + quad*4 + r;
            dst[(rowbase + m)*DIM + cg] = f2bu(accs[nt][r] + bias);
        }
    }
}

// ------- dyn+comb: lane j owns pair (i,j); b-tile staged in LDS -------------
__global__ void __launch_bounds__(256) k_dyn_comb(const ushort_t* __restrict__ aab,
                           const ushort_t* __restrict__ bbb,
                           const float* __restrict__ w2, const float* __restrict__ b2arr,
                           const float* __restrict__ sbase,
                           ushort_t* __restrict__ combb)
{
    int blk = blockIdx.x;                     // 5*16*16 blocks, 4 i-rows each
    int k = blk / (BATCH*16);
    int b = (blk / 16) % BATCH;
    int i0 = (blk % 16) * 4;
    int kb = k*BATCH + b;
    __shared__ ushort_t bs[64][260];          // [j][d], pad keeps 8B row align
    __shared__ float arows[4][DIM];
    __shared__ float w2s[DIM];
    int tid = threadIdx.x;
    int wave = tid >> 6, lane = tid & 63;
    const ushort_t* bsrc = bbb + (size_t)kb*NNODE*DIM;
    for (int u=0; u<16; ++u){
        int idx = u*1024 + tid*4;
        int row = idx >> 8, col = idx & 255;
        *reinterpret_cast<ushort4*>(&bs[row][col]) =
            *reinterpret_cast<const ushort4*>(&bsrc[(size_t)row*DIM + col]);
    }
    for (int r=0;r<4;r++) arows[r][tid] = bu2f(aab[((size_t)kb*NNODE + i0 + r)*DIM + tid]);
    w2s[tid] = w2[k*DIM + tid];
    __syncthreads();

    int i = i0 + wave;
    float acc = 0.f;
    #pragma unroll 4
    for (int dd=0; dd<64; ++dd){
        ushort4 bv = *reinterpret_cast<const ushort4*>(&bs[lane][dd*4]);
        float4 av = *reinterpret_cast<const float4*>(&arows[wave][dd*4]);
        float4 wv = *reinterpret_cast<const float4*>(&w2s[dd*4]);
        float v0 = av.x + bu2f(bv.x);
        float v1 = av.y + bu2f(bv.y);
        float v2 = av.z + bu2f(bv.z);
        float v3 = av.w + bu2f(bv.w);
        float e0 = (v0>0.f)? v0 : (__expf(v0)-1.f);
        float e1 = (v1>0.f)? v1 : (__expf(v1)-1.f);
        float e2 = (v2>0.f)? v2 : (__expf(v2)-1.f);
        float e3 = (v3>0.f)? v3 : (__expf(v3)-1.f);
        acc += e0*wv.x + e1*wv.y + e2*wv.z + e3*wv.w;
    }
    float sb2 = b2arr[k];
    float sg = 1.f/(1.f + __expf(-(acc + sb2)));
    float val = sbase[(k*NNODE + i)*NNODE + lane] + sg;
    float m = val;
    for (int o=32;o>0;o>>=1) m = fmaxf(m, __shfl_xor(m,o,64));
    float e = __expf(val - m);
    float s = e;
    for (int o=32;o>0;o>>=1) s += __shfl_xor(s,o,64);
    combb[((size_t)kb*NNODE + i)*NNODE + lane] = f2bu(e/s);
}

// ---- MFMA y: per (k,b) GEMM [64 x 64] @ [64 x 256] -> yb bf16 [kb][n][d] ----
__global__ void __launch_bounds__(256) k_y_mfma(const ushort_t* __restrict__ combb,
                       const ushort_t* __restrict__ xtT,
                       ushort_t* __restrict__ yb)
{
    int blk = blockIdx.x;                 // 5*16*4
    int kband = blk / (BATCH*4);
    int b = (blk/4) % BATCH;
    int nblk = blk & 3;
    int tid = threadIdx.x;
    int wave = tid>>6, lane = tid&63;
    int c16 = lane & 15, quad = lane >> 4;
    int m0 = wave*16;
    int kb = kband*BATCH + b;
    const ushort_t* Aptr = combb + ((size_t)kb*NNODE + m0 + c16)*NNODE + quad*8;  // [n][j]
    const ushort_t* Bbase = xtT + (size_t)kb*DIM*NNODE;                            // [d][j]
    int ncol0 = nblk*64;
    const ushort_t* Bptr0 = Bbase + (size_t)(ncol0 +  0 + c16)*NNODE + quad*8;
    const ushort_t* Bptr1 = Bbase + (size_t)(ncol0 + 16 + c16)*NNODE + quad*8;
    const ushort_t* Bptr2 = Bbase + (size_t)(ncol0 + 32 + c16)*NNODE + quad*8;
    const ushort_t* Bptr3 = Bbase + (size_t)(ncol0 + 48 + c16)*NNODE + quad*8;
    float4v acc0 = {0.f,0.f,0.f,0.f}, acc1 = acc0, acc2 = acc0, acc3 = acc0;
    #pragma unroll
    for (int ks=0; ks<2; ++ks){
        short8 a  = *reinterpret_cast<const short8*>(Aptr  + ks*32);
        short8 b0 = *reinterpret_cast<const short8*>(Bptr0 + ks*32);
        short8 b1v= *reinterpret_cast<const short8*>(Bptr1 + ks*32);
        short8 b2 = *reinterpret_cast<const short8*>(Bptr2 + ks*32);
        short8 b3 = *reinterpret_cast<const short8*>(Bptr3 + ks*32);
        acc0 = __builtin_amdgcn_mfma_f32_16x16x32_bf16(a, b0, acc0, 0,0,0);
        acc1 = __builtin_amdgcn_mfma_f32_16x16x32_bf16(a, b1v, acc1, 0,0,0);
        acc2 = __builtin_amdgcn_mfma_f32_16x16x32_bf16(a, b2, acc2, 0,0,0);
        acc3 = __builtin_amdgcn_mfma_f32_16x16x32_bf16(a, b3, acc3, 0,0,0);
    }
    size_t rowbase = (size_t)kb*NNODE;
    float4v accs[4] = {acc0, acc1, acc2, acc3};
    #pragma unroll
    for (int nt=0; nt<4; ++nt){
        int cg = ncol0 + nt*16 + c16;
        #pragma unroll
        for (int r=0;r<4;r++){
            int m = m0 + quad*4 + r;
            yb[(rowbase + m)*DIM + cg] = f2bu(accs[nt][r]);
        }
    }
}

// ---- MFMA gcn + fused scale/importance: [64x256]@[256x256]+bias ----
// writes out_local f32 [b,k,d,n], scalew [b,k,d] (mean over n), impw (dot imp_w)
__global__ void __launch_bounds__(256) k_gcn_mfma(const ushort_t* __restrict__ yb,
                         const ushort_t* __restrict__ gwbt, const float* __restrict__ gb,
                         const float* __restrict__ imp_w,
                         float* __restrict__ out_local,
                         float* __restrict__ scalew, float* __restrict__ impw)
{
    int blk = blockIdx.x;                 // 5*16*4
    int kband = blk / (BATCH*4);
    int b = (blk/4) % BATCH;
    int nblk = blk & 3;
    int tid = threadIdx.x;
    int wave = tid>>6, lane = tid&63;
    int c16 = lane & 15, quad = lane >> 4;
    int m0 = wave*16;
    int kb = kband*BATCH + b;
    __shared__ float iw_s[NNODE];
    __shared__ float sred[4][64];
    __shared__ float ired[4][64];
    if (tid < NNODE) iw_s[tid] = imp_w[kband*NNODE + tid];
    const ushort_t* Aptr = yb + ((size_t)kb*NNODE + m0 + c16)*DIM + quad*8;  // [n][d]
    const ushort_t* Bbase = gwbt + (size_t)kband*DIM*DIM;                    // [col][kk]
    int ncol0 = nblk*64;
    const ushort_t* Bptr0 = Bbase + (size_t)(ncol0 +  0 + c16)*DIM + quad*8;
    const ushort_t* Bptr1 = Bbase + (size_t)(ncol0 + 16 + c16)*DIM + quad*8;
    const ushort_t* Bptr2 = Bbase + (size_t)(ncol0 + 32 + c16)*DIM + quad*8;
    const ushort_t* Bptr3 = Bbase + (size_t)(ncol0 + 48 + c16)*DIM + quad*8;
    float4v acc0 = {0.f,0.f,0.f,0.f}, acc1 = acc0, acc2 = acc0, acc3 = acc0;
    #pragma unroll
    for (int ks=0; ks<8; ++ks){
        short8 a  = *reinterpret_cast<const short8*>(Aptr  + ks*32);
        short8 b0 = *reinterpret_cast<const short8*>(Bptr0 + ks*32);
        short8 b1v= *reinterpret_cast<const short8*>(Bptr1 + ks*32);
        short8 b2 = *reinterpret_cast<const short8*>(Bptr2 + ks*32);
        short8 b3 = *reinterpret_cast<const short8*>(Bptr3 + ks*32);
        acc0 = __builtin_amdgcn_mfma_f32_16x16x32_bf16(a, b0, acc0, 0,0,0);
        acc1 = __builtin_amdgcn_mfma_f32_16x16x32_bf16(a, b1v, acc1, 0,0,0);
        acc2 = __builtin_amdgcn_mfma_f32_16x16x32_bf16(a, b2, acc2, 0,0,0);
        acc3 = __builtin_amdgcn_mfma_f32_16x16x32_bf16(a, b3, acc3, 0,0,0);
    }
    __syncthreads();   // iw_s visible
    float4v accs[4] = {acc0, acc1, acc2, acc3};
    #pragma unroll
    for (int nt=0; nt<4; ++nt){
        int cg = ncol0 + nt*16 + c16;
        float bias = gb[kband*DIM + cg];
        float v0 = accs[nt][0]+bias, v1 = accs[nt][1]+bias, v2 = accs[nt][2]+bias, v3 = accs[nt][3]+bias;
        // out_local store
        float4 v = make_float4(v0, v1, v2, v3);
        float* dst = out_local + ((size_t)(b*NBANDS + kband)*DIM + cg)*NNODE + m0 + quad*4;
        *reinterpret_cast<float4*>(dst) = v;
        // per-thread partials over its 4 n's
        int nb = m0 + quad*4;
        float s  = v0 + v1 + v2 + v3;
        float di = v0*iw_s[nb] + v1*iw_s[nb+1] + v2*iw_s[nb+2] + v3*iw_s[nb+3];
        // reduce over quads (lane bits 4,5)
        s  += __shfl_xor(s, 16, 64);  s  += __shfl_xor(s, 32, 64);
        di += __shfl_xor(di, 16, 64); di += __shfl_xor(di, 32, 64);
        if (quad == 0){
            sred[wave][nt*16 + c16] = s;
            ired[wave][nt*16 + c16] = di;
        }
    }
    __syncthreads();
    if (tid < 64){
        float s  = sred[0][tid] + sred[1][tid] + sred[2][tid] + sred[3][tid];
        float di = ired[0][tid] + ired[1][tid] + ired[2][tid] + ired[3][tid];
        size_t o = ((size_t)b*SEQ + kband)*DIM + ncol0 + tid;
        scalew[o] = s * (1.f/64.f);
        impw[o]   = di;
    }
}

// ---- generic sliced GEMV: out[row][n] = act(bias[n] + sum_k x[row][k] w[k][n]) ----
template<int COLS, int SLICES>
__global__ void __launch_bounds__(256) k_gemv(const float* __restrict__ x, const float* __restrict__ w,
                       const float* __restrict__ bias, float* __restrict__ out,
                       int K, int N, int act)
{
    int chunks = N / COLS;
    int row = blockIdx.x / chunks;
    int n0 = (blockIdx.x % chunks) * COLS;
    int c = threadIdx.x % COLS, s = threadIdx.x / COLS;
    __shared__ float xs[1024];
    __shared__ float part[SLICES][COLS];
    for (int i = threadIdx.x; i < K; i += 256) xs[i] = x[(size_t)row*K + i];
    __syncthreads();
    int klen = K / SLICES;
    const float* wp = w + (size_t)(s*klen)*N + n0 + c;
    const float* xp = xs + s*klen;
    float acc = 0.f;
    #pragma unroll 8
    for (int i = 0; i < klen; ++i) acc += xp[i] * wp[(size_t)i*N];
    part[s][c] = acc;
    __syncthreads();
    if (s == 0){
        float v = bias[n0+c];
        #pragma unroll
        for (int q=0;q<SLICES;q++) v += part[q][c];
        if (act) v = 0.5f*v*(1.f + erff(v*0.70710678118654752f));
        out[(size_t)row*N + n0 + c] = v;
    }
}

// ---- proj with fused per-row attention prologue ----------------------------
__global__ void __launch_bounds__(256) k_projattn(const float* __restrict__ qkvw,
                        const float* __restrict__ ow, const float* __restrict__ ob,
                        float* __restrict__ projw)
{
    int row = blockIdx.x / 4;            // b*SEQ + i
    int n0 = (blockIdx.x % 4) * 64;
    int b = row / SEQ, i = row % SEQ;
    int tid = threadIdx.x;
    int h = tid >> 6, l = tid & 63;
    __shared__ float xs[DIM];
    __shared__ float part[4][64];
    const float* base = qkvw + (size_t)b*SEQ*3*DIM;
    // attention row i, head h (butterfly leaves sum in all lanes)
    float qv = base[(size_t)i*3*DIM + h*DHEAD + l];
    float pj[SEQ];
    #pragma unroll
    for (int j=0;j<SEQ;j++){
        float p = qv * base[(size_t)j*3*DIM + DIM + h*DHEAD + l];
        for (int o=32;o>0;o>>=1) p += __shfl_xor(p,o,64);
        pj[j] = p * 0.125f;
    }
    float m = pj[0];
    #pragma unroll
    for (int j=1;j<SEQ;j++) m = fmaxf(m, pj[j]);
    float ssum = 0.f;
    #pragma unroll
    for (int j=0;j<SEQ;j++){ pj[j] = __expf(pj[j]-m); ssum += pj[j]; }
    float inv = 1.f/ssum;
    float o = 0.f;
    #pragma unroll
    for (int j=0;j<SEQ;j++) o += pj[j]*inv * base[(size_t)j*3*DIM + 2*DIM + h*DHEAD + l];
    xs[tid] = o;
    __syncthreads();
    // proj chunk gemv
    int c = tid & 63, s = tid >> 6;
    const float* wp = ow + (size_t)(s*64)*DIM + n0 + c;
    const float* xp = xs + s*64;
    float acc = 0.f;
    #pragma unroll 8
    for (int k=0;k<64;++k) acc += xp[k] * wp[(size_t)k*DIM];
    part[s][c] = acc;
    __syncthreads();
    if (s == 0){
        projw[(size_t)row*DIM + n0 + c] = ob[n0+c] + part[0][c]+part[1][c]+part[2][c]+part[3][c];
    }
}

// ---------------- block LayerNorm over 256 elems ----------------------------
__device__ __forceinline__ float block_ln(float v, int tid, float* red, float g, float bln)
{
    float s = v;
    for (int o=32;o>0;o>>=1) s += __shfl_xor(s,o,64);
    int wave = tid>>6, lane = tid&63;
    if (lane==0) red[wave] = s;
    __syncthreads();
    float mean = (red[0]+red[1]+red[2]+red[3]) * (1.f/DIM);
    float c = v - mean;
    float q = c*c;
    for (int o=32;o>0;o>>=1) q += __shfl_xor(q,o,64);
    __syncthreads();
    if (lane==0) red[wave] = q;
    __syncthreads();
    float var = (red[0]+red[1]+red[2]+red[3]) * (1.f/DIM);
    return c * rsqrtf(var + 1e-5f) * g + bln;
}

// ---- mlp1 with fused LN1 prologue ------------------------------------------
__global__ void __launch_bounds__(256) k_mlp1_ln(const float* __restrict__ projw,
                         const float* __restrict__ scalew,
                         const float* __restrict__ ln1_g, const float* __restrict__ ln1_b,
                         const float* __restrict__ w1, const float* __restrict__ b1,
                         float* __restrict__ h1w, float* __restrict__ mhw)
{
    int row = blockIdx.x / 16;
    int n0 = (blockIdx.x % 16) * 64;
    int tid = threadIdx.x;
    __shared__ float xs[DIM];
    __shared__ float red[4];
    __shared__ float part[4][64];
    float v = projw[(size_t)row*DIM + tid] + scalew[(size_t)row*DIM + tid];
    float h = block_ln(v, tid, red, ln1_g[tid], ln1_b[tid]);
    xs[tid] = h;
    if ((blockIdx.x % 16) == 0) h1w[(size_t)row*DIM + tid] = h;
    __syncthreads();
    int c = tid & 63, s = tid >> 6;
    const float* wp = w1 + (size_t)(s*64)*1024 + n0 + c;
    const float* xp = xs + s*64;
    float acc = 0.f;
    #pragma unroll 8
    for (int i=0;i<64;++i) acc += xp[i] * wp[(size_t)i*1024];
    part[s][c] = acc;
    __syncthreads();
    if (s == 0){
        float o = b1[n0+c] + part[0][c] + part[1][c] + part[2][c] + part[3][c];
        o = 0.5f*o*(1.f + erff(o*0.70710678118654752f));
        mhw[(size_t)row*1024 + n0 + c] = o;
    }
}

// ---- gab with fused LN2 prologue -------------------------------------------
__global__ void __launch_bounds__(256) k_gab_ln(const float* __restrict__ m2w,
                        const float* __restrict__ h1w,
                        const float* __restrict__ ln2_g, const float* __restrict__ ln2_b,
                        const float* __restrict__ gw1, const float* __restrict__ gb1,
                        float* __restrict__ sew, float* __restrict__ gaw, float* __restrict__ gbw)
{
    int row = blockIdx.x / 4;
    int n0 = (blockIdx.x % 4) * 64;
    int tid = threadIdx.x;
    __shared__ float xs[DIM];
    __shared__ float red[4];
    __shared__ float partA[4][64];
    __shared__ float partB[4][64];
    float v = m2w[(size_t)row*DIM + tid] + h1w[(size_t)row*DIM + tid];
    float h = block_ln(v, tid, red, ln2_g[tid], ln2_b[tid]);
    xs[tid] = h;
    if ((blockIdx.x % 4) == 0) sew[(size_t)row*DIM + tid] = h;
    __syncthreads();
    int c = tid & 63, s = tid >> 6;
    const float* wpA = gw1 + (size_t)(s*64)*DIM + n0 + c;
    const float* wpB = wpA + (size_t)DIM*DIM;
    const float* xp = xs + s*64;
    float aA = 0.f, aB = 0.f;
    #pragma unroll 8
    for (int i=0;i<64;++i){
        float xv = xp[i];
        aA += xv * wpA[(size_t)i*DIM];
        aB += xv * wpB[(size_t)i*DIM];
    }
    partA[s][c] = aA;
    partB[s][c] = aB;
    __syncthreads();
    if (s == 0){
        gaw[(size_t)row*DIM + n0 + c] = gb1[n0+c] + partA[0][c]+partA[1][c]+partA[2][c]+partA[3][c];
        gbw[(size_t)row*DIM + n0 + c] = partB[0][c]+partB[1][c]+partB[2][c]+partB[3][c];
    }
}

// ---- gout with fused gadj + gmix + final modulation ------------------------
__global__ void __launch_bounds__(256) k_goutfin(const float* __restrict__ gaw,
                        const float* __restrict__ gbw,
                        const float* __restrict__ gw2, const float* __restrict__ gb2,
                        const float* __restrict__ gbase,
                        const float* __restrict__ sew,
                        const float* __restrict__ ggw, const float* __restrict__ ggb,
                        const float* __restrict__ impw, const float* __restrict__ imp_b,
                        float* __restrict__ out0, float* __restrict__ out_gadj)
{
    int row = blockIdx.x / 4;            // b*SEQ + i
    int n0 = (blockIdx.x % 4) * 64;
    int b = row / SEQ, i = row % SEQ;
    int tid = threadIdx.x;
    int wave = tid >> 6, lane = tid & 63;
    __shared__ float dyn_s[SEQ];
    __shared__ float xs[DIM];
    __shared__ float part[4][64];
    // dyn row i: wave j handles column j (wave 0 also j=4)
    for (int j = wave; j < SEQ; j += 4){
        const float* gar = gaw + (size_t)row*DIM;
        const float* gbr = gbw + ((size_t)b*SEQ + j)*DIM;
        float acc = 0.f;
        #pragma unroll
        for (int m=0;m<4;m++){
            int dd = lane + m*64;
            float v = gar[dd] + gbr[dd];
            float e = (v>0.f) ? v : (__expf(v)-1.f);
            acc += e * gw2[dd];
        }
        for (int o=32;o>0;o>>=1) acc += __shfl_xor(acc,o,64);
        if (lane==0) dyn_s[j] = acc;
    }
    __syncthreads();
    // softmax row (redundant in all threads)
    float gc[SEQ];
    {
        float sb2 = gb2[0];
        float m = -1e30f;
        #pragma unroll
        for (int j=0;j<SEQ;j++){
            float sg = 1.f/(1.f+__expf(-(dyn_s[j]+sb2)));
            gc[j] = gbase[i*SEQ+j] + sg;
            m = fmaxf(m, gc[j]);
        }
        float ssum=0.f;
        #pragma unroll
        for (int j=0;j<SEQ;j++){ gc[j]=__expf(gc[j]-m); ssum+=gc[j]; }
        float inv = 1.f/ssum;
        #pragma unroll
        for (int j=0;j<SEQ;j++) gc[j] *= inv;
    }
    if (n0 == 0 && tid < SEQ) out_gadj[((size_t)b*SEQ+i)*SEQ + tid] = gc[tid];
    // gmix
    float t = 0.f;
    #pragma unroll
    for (int j=0;j<SEQ;j++) t += gc[j]*sew[((size_t)b*SEQ + j)*DIM + tid];
    xs[tid] = t;
    __syncthreads();
    // gout chunk gemv + final modulation
    int c = tid & 63, s = tid >> 6;
    const float* wp = ggw + (size_t)(s*64)*DIM + n0 + c;
    const float* xp = xs + s*64;
    float acc = 0.f;
    #pragma unroll 8
    for (int k=0;k<64;++k) acc += xp[k] * wp[(size_t)k*DIM];
    part[s][c] = acc;
    __syncthreads();
    if (s == 0){
        float g = ggb[n0+c] + part[0][c]+part[1][c]+part[2][c]+part[3][c];
        size_t o = (size_t)row*DIM + n0 + c;
        out0[o] = g * impw[o] + imp_b[i];
    }
}

extern "C" void kernel_launch(void* const* d_in, const int* in_sizes, int n_in,
                              void* d_out, int out_size, void* d_ws, size_t ws_size,
                              hipStream_t stream)
{
    const float* feature      = (const float*)d_in[0];
    const float* l_adj_w      = (const float*)d_in[1];
    const float* l_sim_w1     = (const float*)d_in[2];
    const float* l_sim_b1     = (const float*)d_in[3];
    const float* l_sim_w2     = (const float*)d_in[4];
    const float* l_sim_b2     = (const float*)d_in[5];
    const float* l_pos_factor = (const float*)d_in[6];
    const float* l_pos_enc    = (const float*)d_in[7];
    const float* l_gcn_w      = (const float*)d_in[8];
    const float* l_gcn_b      = (const float*)d_in[9];
    const float* g_adj_w      = (const float*)d_in[10];
    const float* g_sim_w1     = (const float*)d_in[11];
    const float* g_sim_b1     = (const float*)d_in[12];
    const float* g_sim_w2     = (const float*)d_in[13];
    const float* g_sim_b2     = (const float*)d_in[14];
    const float* g_pos_factor = (const float*)d_in[15];
    const float* g_pos_enc    = (const float*)d_in[16];
    const float* g_gcn_w      = (const float*)d_in[17];
    const float* g_gcn_b      = (const float*)d_in[18];
    const float* qkv_w        = (const float*)d_in[19];
    const float* qkv_b        = (const float*)d_in[20];
    const float* attn_ow      = (const float*)d_in[21];
    const float* attn_ob      = (const float*)d_in[22];
    const float* ln1_g        = (const float*)d_in[23];
    const float* ln1_b        = (const float*)d_in[24];
    const float* ln2_g        = (const float*)d_in[25];
    const float* ln2_b        = (const float*)d_in[26];
    const float* mlp_w1       = (const float*)d_in[27];
    const float* mlp_b1       = (const float*)d_in[28];
    const float* mlp_w2       = (const float*)d_in[29];
    const float* mlp_b2       = (const float*)d_in[30];
    const float* imp_w        = (const float*)d_in[31];
    const float* imp_b        = (const float*)d_in[32];

    float* out0      = (float*)d_out;
    float* out_gadj  = out0 + (size_t)BATCH*NBANDS*DIM;
    float* out_local = out_gadj + (size_t)BATCH*NBANDS*NBANDS;

    const size_t BIG = (size_t)NBANDS*BATCH*NNODE*DIM;           // 1,310,720 elems
    ushort_t* xtb   = (ushort_t*)d_ws;                           // bf16 [k,b,n,d]
    ushort_t* aab   = xtb + BIG;                                 // bf16 a (reused as y)
    ushort_t* bbb   = aab + BIG;                                 // bf16 bp
    ushort_t* xtT   = bbb + BIG;                                 // bf16 [k,b,d,n]
    ushort_t* yb    = aab;
    ushort_t* w1bt  = xtT + BIG;                                 // bf16 [k][512][256]
    ushort_t* gwbt  = w1bt + (size_t)NBANDS*512*DIM;             // bf16 [k][256][256]
    ushort_t* combb = gwbt + (size_t)NBANDS*DIM*DIM;             // bf16 [kb][64][64]
    float* fp = (float*)(combb + (size_t)NBANDS*BATCH*NNODE*NNODE);
    float* sbase  = fp; fp += NBANDS*NNODE*NNODE;
    float* gbase  = fp; fp += 32;
    float* scalew = fp; fp += BATCH*SEQ*DIM;
    float* impw   = fp; fp += BATCH*SEQ*DIM;
    float* qkvw   = fp; fp += BATCH*SEQ*3*DIM;
    float* projw  = fp; fp += BATCH*SEQ*DIM;
    float* h1w    = fp; fp += BATCH*SEQ*DIM;
    float* mhw    = fp; fp += BATCH*SEQ*4*DIM;
    float* m2w    = fp; fp += BATCH*SEQ*DIM;
    float* sew    = fp; fp += BATCH*SEQ*DIM;
    float* gaw    = fp; fp += BATCH*SEQ*DIM;
    float* gbw    = fp; fp += BATCH*SEQ*DIM;

    const int ROWS = BATCH*SEQ;   // 80

    k_head<<<641, 256, 0, stream>>>(l_adj_w, l_pos_enc, l_pos_factor,
                                    g_adj_w, g_pos_enc, g_pos_factor,
                                    sbase, gbase,
                                    l_sim_w1, l_gcn_w, w1bt, gwbt,
                                    feature, xtb, xtT);
    k_ab_mfma<<<NBANDS*BATCH*8, 256, 0, stream>>>(xtb, w1bt, l_sim_b1, aab, bbb);
    k_dyn_comb<<<NBANDS*BATCH*16, 256, 0, stream>>>(aab, bbb, l_sim_w2, l_sim_b2, sbase, combb);
    k_y_mfma<<<NBANDS*BATCH*4, 256, 0, stream>>>(combb, xtT, yb);
    k_gcn_mfma<<<NBANDS*BATCH*4, 256, 0, stream>>>(yb, gwbt, l_gcn_b, imp_w,
                                                   out_local, scalew, impw);
    k_gemv<64,4><<<ROWS*12, 256, 0, stream>>>(scalew, qkv_w, qkv_b, qkvw, 256, 768, 0);
    k_projattn<<<ROWS*4, 256, 0, stream>>>(qkvw, attn_ow, attn_ob, projw);
    k_mlp1_ln<<<ROWS*16, 256, 0, stream>>>(projw, scalew, ln1_g, ln1_b, mlp_w1, mlp_b1, h1w, mhw);
    k_gemv<32,8><<<ROWS*8, 256, 0, stream>>>(mhw, mlp_w2, mlp_b2, m2w, 1024, 256, 0);
    k_gab_ln<<<ROWS*4, 256, 0, stream>>>(m2w, h1w, ln2_g, ln2_b, g_sim_w1, g_sim_b1, sew, gaw, gbw);
    k_goutfin<<<ROWS*4, 256, 0, stream>>>(gaw, gbw, g_sim_w2, g_sim_b2, gbase,
                                          sew, g_gcn_w, g_gcn_b, impw, imp_b,
                                          out0, out_gadj);
}